// Round 6
// baseline (178.298 us; speedup 1.0000x reference)
//
#include <hip/hip_runtime.h>
#include <hip/hip_bf16.h>
#include <stdint.h>

typedef __bf16 bf16_t;
typedef __attribute__((ext_vector_type(8))) __bf16 bf16x8;
typedef __attribute__((ext_vector_type(4))) __bf16 bf16x4;
typedef __attribute__((ext_vector_type(4))) float f32x4;

#define NHEADS 32
#define HDIM 128
#define NKV 8
#define GQ 4
#define BATCH 8
#define SEQ 1024
#define TOTAL (BATCH * SEQ)
#define QD (NHEADS * HDIM)   // 4096
#define KVD (NKV * HDIM)     // 1024
#define ATT_SCALE 0.08838834764831845f
// scale * log2(e): fold into Q so QK^T directly yields exp2 argument.
#define QSCL (0.08838834764831845f * 1.4426950408889634f)

#define QBLK 64
#define KBLK 64
#define NQT (SEQ / QBLK)     // 16

// ---------------------------------------------------------------------------
// global_load_lds helper: 16B per lane, per-lane GLOBAL addr, linear LDS dest
// (wave-uniform base + lane*16).
// ---------------------------------------------------------------------------
__device__ __forceinline__ void gload16(const bf16_t* g, bf16_t* l) {
    __builtin_amdgcn_global_load_lds(
        (const __attribute__((address_space(1))) void*)g,
        (__attribute__((address_space(3))) void*)l,
        16, 0, 0);
}

// ===========================================================================
// Pre-pass: K fp32 -> bf16 (same layout); V fp32 -> bf16 TRANSPOSED
// Vt_ws[((b*8+hk)*128 + d)*1024 + tok].
// ===========================================================================
__global__ __launch_bounds__(256)
void attn_prepass_kernel(const float* __restrict__ kg, const float* __restrict__ vg,
                         bf16_t* __restrict__ kws, bf16_t* __restrict__ vtws)
{
    const int bid = blockIdx.x;
    const int tid = threadIdx.x;
    if (bid < 512) {
        // V transpose tile: (b, hk, tt): tok tt*128..+127  x  d 0..127
        __shared__ bf16_t Lt[128 * 130];   // [d][tok], pad 130
        const int b  = bid >> 6;
        const int hk = (bid >> 3) & 7;
        const int tt = bid & 7;
        const float* vp = vg + ((long)(b * SEQ + tt * 128)) * KVD + hk * HDIM;
        #pragma unroll
        for (int it = 0; it < 16; ++it) {
            int idx = it * 256 + tid;
            int t  = idx >> 5;          // 0..127
            int c4 = (idx & 31) * 4;    // 0..124
            float4 f = *(const float4*)(vp + (long)t * KVD + c4);
            Lt[(c4 + 0) * 130 + t] = (bf16_t)f.x;
            Lt[(c4 + 1) * 130 + t] = (bf16_t)f.y;
            Lt[(c4 + 2) * 130 + t] = (bf16_t)f.z;
            Lt[(c4 + 3) * 130 + t] = (bf16_t)f.w;
        }
        __syncthreads();
        bf16_t* op = vtws + ((long)((b * NKV + hk) * HDIM)) * SEQ + tt * 128;
        #pragma unroll
        for (int jt = 0; jt < 8; ++jt) {
            int jdx = jt * 256 + tid;
            int d  = jdx >> 4;          // 0..127
            int c8 = (jdx & 15) * 8;    // 0..120
            const bf16_t* lp = &Lt[d * 130 + c8];
            uint32_t u0 = *(const uint32_t*)(lp + 0);
            uint32_t u1 = *(const uint32_t*)(lp + 2);
            uint32_t u2 = *(const uint32_t*)(lp + 4);
            uint32_t u3 = *(const uint32_t*)(lp + 6);
            uint4 o; o.x = u0; o.y = u1; o.z = u2; o.w = u3;
            *(uint4*)(op + (long)d * SEQ + c8) = o;
        }
    } else {
        // K convert: grid-stride float4 -> bf16x4
        const long total4 = (long)TOTAL * KVD / 4;   // 2,097,152
        const float4* k4 = (const float4*)kg;
        for (long i = (long)(bid - 512) * 256 + tid; i < total4; i += 1024L * 256) {
            float4 f = k4[i];
            bf16x4 o4;
            o4[0] = (bf16_t)f.x; o4[1] = (bf16_t)f.y;
            o4[2] = (bf16_t)f.z; o4[3] = (bf16_t)f.w;
            *(bf16x4*)(kws + i * 4) = o4;
        }
    }
}

// ===========================================================================
// Main attention kernel (v5): v4's pipeline (global_load_lds dbuf staging,
// swizzled LDS, slim softmax, balanced q-tile pairing) restructured to
// 1024-THREAD / 16-WAVE BLOCKS to double occupancy:
//   r5 diagnosis: arch VGPR 116 + 64 AGPR (accO, unified gfx950 file)
//   ~= 180 regs/lane -> 2 waves/SIMD -> 1 block/CU -> 21% occupancy cap.
//   Now wave w owns 16 q-rows of head (w>>2), slot (w&3): accO 64->32,
//   aq 32->16; live state ~110 < 128. 1024-thread block forces the
//   compiler to the 128-reg budget -> 4 waves/SIMD = 16 waves/CU.
// Staging: 1 K-chunk + 1 V-chunk per wave per tile -> vmcnt(2) steady state.
// ===========================================================================
__global__ __launch_bounds__(1024)
void attn_fwd_v5(const float* __restrict__ qg, const bf16_t* __restrict__ kws,
                 const bf16_t* __restrict__ vtws, float* __restrict__ og)
{
    __shared__ __align__(16) bf16_t Kl[2][KBLK * HDIM];   // [64][128] rows 256B
    __shared__ __align__(16) bf16_t Vl[2][HDIM * KBLK];   // [128][64] rows 128B
    __shared__ __align__(16) bf16_t Pl[16][16 * 64];      // per-wave [16][64] rows 128B

    const int tid  = threadIdx.x;
    const int w    = tid >> 6;    // 0..15
    const int lane = tid & 63;
    const int l4   = lane >> 4;   // 0..3
    const int l16  = lane & 15;   // 0..15

    const int bid = blockIdx.x;   // 0..511
    const int bh  = bid & 63;
    const int pi  = bid >> 6;     // 0..7
    const int b   = bh >> 3;
    const int hk  = bh & 7;
    const int g   = w >> 2;       // head within kv group
    const int fs  = w & 3;        // 16-row slot within the 64-row q-tile
    const int h   = hk * GQ + g;

    const bf16_t* kbase = kws + (long)(b * SEQ) * KVD + hk * HDIM;
    const bf16_t* vbase = vtws + (long)((b * NKV + hk) * HDIM) * SEQ;

    // Stage one K/V tile: wave w loads K chunk w (1KB) + V chunk w (1KB).
    auto issue_tile = [&](int buf, int kt) {
        {
            int r = w * 4 + (lane >> 4);
            const bf16_t* gp = kbase + (long)(kt * KBLK + r) * KVD + (((lane & 15) ^ (r & 7)) * 8);
            gload16(gp, &Kl[buf][w * 512]);
        }
        {
            int d = w * 8 + (lane >> 3);
            const bf16_t* gp = vbase + (long)d * SEQ + kt * KBLK + (((lane & 7) ^ (d & 7)) * 8);
            gload16(gp, &Vl[buf][w * 512]);
        }
    };

    for (int ph = 0; ph < 2; ++ph) {
        const int qt = ph ? pi : (NQT - 1 - pi);   // heavy q-tile first, then light
        const long qtok0 = (long)b * SEQ + qt * QBLK;

        // ---- Q fragments in registers, pre-scaled by scale*log2e ----
        bf16x8 aq[4];
        {
            const float* qp = qg + (qtok0 + fs * 16 + l16) * QD + h * HDIM + l4 * 8;
            #pragma unroll
            for (int s = 0; s < 4; ++s) {
                float4 x = *(const float4*)(qp + s * 32);
                float4 y = *(const float4*)(qp + s * 32 + 4);
                bf16x8 t;
                t[0] = (bf16_t)(x.x * QSCL); t[1] = (bf16_t)(x.y * QSCL);
                t[2] = (bf16_t)(x.z * QSCL); t[3] = (bf16_t)(x.w * QSCL);
                t[4] = (bf16_t)(y.x * QSCL); t[5] = (bf16_t)(y.y * QSCL);
                t[6] = (bf16_t)(y.z * QSCL); t[7] = (bf16_t)(y.w * QSCL);
                aq[s] = t;
            }
        }
        // Pin Q loads BEFORE staging issues so manual vmcnt counts are correct.
        __builtin_amdgcn_sched_barrier(0);

        f32x4 accO[8];
        f32x4 rsum;
        #pragma unroll
        for (int n = 0; n < 8; ++n) accO[n] = (f32x4){0.f, 0.f, 0.f, 0.f};
        rsum = (f32x4){0.f, 0.f, 0.f, 0.f};

        const int nkt = qt + 1;
        issue_tile(0, 0);
        if (nkt > 1) issue_tile(1, 1);

        for (int kt = 0; kt < nkt; ++kt) {
            const int cur = kt & 1;
            // Tile kt landed when only tile kt+1's 2 loads remain outstanding.
            if (kt + 1 < nkt) asm volatile("s_waitcnt vmcnt(2)" ::: "memory");
            else              asm volatile("s_waitcnt vmcnt(0)" ::: "memory");
            __builtin_amdgcn_s_barrier();
            __builtin_amdgcn_sched_barrier(0);

            const bool diag = (kt == qt);
            bf16_t* pw = &Pl[w][0];
            const bf16_t* Kc = &Kl[cur][0];
            const bf16_t* Vc = &Vl[cur][0];

            // ---- S' = (Q*scale*log2e) K^T : D[q=l4*4+j][kcol=n*16+l16] ----
            f32x4 accS[4];
            __builtin_amdgcn_s_setprio(1);
            #pragma unroll
            for (int n = 0; n < 4; ++n) {
                f32x4 acc = (f32x4){0.f, 0.f, 0.f, 0.f};
                const int r = n * 16 + l16;
                #pragma unroll
                for (int s = 0; s < 4; ++s) {
                    int cb = ((s * 64 + l4 * 16) ^ ((r & 7) << 4)) >> 1;
                    bf16x8 bk = *(const bf16x8*)(Kc + r * 128 + cb);
                    acc = __builtin_amdgcn_mfma_f32_16x16x32_bf16(aq[s], bk, acc, 0, 0, 0);
                }
                accS[n] = acc;
            }
            __builtin_amdgcn_s_setprio(0);

            // ---- slim softmax: p = exp2(S'), zero masked, accumulate sum ----
            const int qrow_loc = fs * 16 + l4 * 4;   // + j
            if (diag) {
                #pragma unroll
                for (int n = 0; n < 4; ++n) {
                    #pragma unroll
                    for (int j = 0; j < 4; ++j) {
                        float p = exp2f(accS[n][j]);
                        if (n * 16 + l16 > qrow_loc + j) p = 0.f;
                        accS[n][j] = p;
                        rsum[j] += p;
                    }
                }
            } else {
                #pragma unroll
                for (int n = 0; n < 4; ++n) {
                    #pragma unroll
                    for (int j = 0; j < 4; ++j) {
                        float p = exp2f(accS[n][j]);
                        accS[n][j] = p;
                        rsum[j] += p;
                    }
                }
            }

            // ---- P -> per-wave LDS (swizzled [16][64]) ----
            #pragma unroll
            for (int n = 0; n < 4; ++n) {
                #pragma unroll
                for (int j = 0; j < 4; ++j) {
                    int qr = l4 * 4 + j;
                    int cbyte = (n * 32 + l16 * 2) ^ ((qr & 7) << 4);
                    pw[qr * 64 + (cbyte >> 1)] = (bf16_t)accS[n][j];
                }
            }
            asm volatile("s_waitcnt lgkmcnt(0)" ::: "memory");
            __builtin_amdgcn_sched_barrier(0);
            // ---- O += P V : swizzled P (A) and Vt (B) reads ----
            __builtin_amdgcn_s_setprio(1);
            #pragma unroll
            for (int ks = 0; ks < 2; ++ks) {
                int cbp = ((ks * 64 + l4 * 16) ^ ((l16 & 7) << 4)) >> 1;
                bf16x8 ap = *(const bf16x8*)(pw + l16 * 64 + cbp);
                #pragma unroll
                for (int n = 0; n < 8; ++n) {
                    int d = n * 16 + l16;
                    int cb = ((ks * 64 + l4 * 16) ^ ((d & 7) << 4)) >> 1;
                    bf16x8 bv = *(const bf16x8*)(Vc + d * 64 + cb);
                    accO[n] = __builtin_amdgcn_mfma_f32_16x16x32_bf16(ap, bv, accO[n], 0, 0, 0);
                }
            }
            __builtin_amdgcn_s_setprio(0);

            __builtin_amdgcn_sched_barrier(0);
            __builtin_amdgcn_s_barrier();
            if (kt + 2 < nkt) issue_tile(cur, kt + 2);
        }

        // ---- epilogue: cross-lane sum reduce, normalize, store fp32 ----
        #pragma unroll
        for (int j = 0; j < 4; ++j) {
            float r = rsum[j];
            r += __shfl_xor(r, 1);
            r += __shfl_xor(r, 2);
            r += __shfl_xor(r, 4);
            r += __shfl_xor(r, 8);
            float inv = 1.f / r;
            float* op = og + (qtok0 + fs * 16 + l4 * 4 + j) * QD + h * HDIM;
            #pragma unroll
            for (int n = 0; n < 8; ++n)
                op[n * 16 + l16] = accO[n][j] * inv;
        }
    }
}

// ===========================================================================
// Fallback (round-1 kernel) if ws is too small for the bf16 pre-pass.
// ===========================================================================
#define KPAD 136
#define VPAD 72
#define PPAD 72
__global__ __launch_bounds__(512, 2)
void attn_fwd_v1(const float* __restrict__ qg, const float* __restrict__ kg,
                 const float* __restrict__ vg, float* __restrict__ og)
{
    __shared__ bf16_t Kl[KBLK * KPAD];
    __shared__ bf16_t Vt[HDIM * VPAD];
    __shared__ bf16_t Pl[8 * 16 * PPAD];

    const int tid  = threadIdx.x;
    const int w    = tid >> 6;
    const int lane = tid & 63;
    const int l4   = lane >> 4;
    const int l16  = lane & 15;

    const int bid = blockIdx.x;
    const int bh  = bid % 64;
    const int qt  = (NQT - 1) - bid / 64;
    const int b   = bh / NKV;
    const int hk  = bh % NKV;
    const int g   = w >> 1;
    const int h   = hk * GQ + g;
    const int rh  = (w & 1) * 32;

    const long qtok0 = (long)b * SEQ + qt * QBLK;

    bf16x8 aq[2][4];
    #pragma unroll
    for (int f = 0; f < 2; ++f) {
        const float* qp = qg + (qtok0 + rh + f * 16 + l16) * QD + h * HDIM + l4 * 8;
        #pragma unroll
        for (int s = 0; s < 4; ++s) {
            float4 x = *(const float4*)(qp + s * 32);
            float4 y = *(const float4*)(qp + s * 32 + 4);
            bf16x8 t;
            t[0] = (bf16_t)x.x; t[1] = (bf16_t)x.y; t[2] = (bf16_t)x.z; t[3] = (bf16_t)x.w;
            t[4] = (bf16_t)y.x; t[5] = (bf16_t)y.y; t[6] = (bf16_t)y.z; t[7] = (bf16_t)y.w;
            aq[f][s] = t;
        }
    }

    f32x4 accO[2][8];
    float mrun[2][4], lsum[2][4];
    #pragma unroll
    for (int f = 0; f < 2; ++f) {
        #pragma unroll
        for (int n = 0; n < 8; ++n) accO[f][n] = (f32x4){0.f, 0.f, 0.f, 0.f};
        #pragma unroll
        for (int j = 0; j < 4; ++j) { mrun[f][j] = -1e30f; lsum[f][j] = 0.f; }
    }

    const long ktok0 = (long)b * SEQ;
    const int nkt = qt + 1;

    for (int kt = 0; kt < nkt; ++kt) {
        __syncthreads();
        const float* kp = kg + (ktok0 + kt * KBLK) * KVD + hk * HDIM;
        const float* vp = vg + (ktok0 + kt * KBLK) * KVD + hk * HDIM;
        #pragma unroll
        for (int it = 0; it < 4; ++it) {
            int idx = it * 512 + tid;
            int row = idx >> 5;
            int c4  = (idx & 31) * 4;
            float4 kf = *(const float4*)(kp + (long)row * KVD + c4);
            bf16x4 k4;
            k4[0] = (bf16_t)kf.x; k4[1] = (bf16_t)kf.y; k4[2] = (bf16_t)kf.z; k4[3] = (bf16_t)kf.w;
            *(bf16x4*)(&Kl[row * KPAD + c4]) = k4;
            float4 vf = *(const float4*)(vp + (long)row * KVD + c4);
            const float* vfa = (const float*)&vf;
            #pragma unroll
            for (int m = 0; m < 4; ++m) {
                int d   = c4 + m;
                int blk = (row >> 3) ^ ((d >> 3) & 7);
                Vt[d * VPAD + blk * 8 + (row & 7)] = (bf16_t)vfa[m];
            }
        }
        __syncthreads();

        const bool diag = (kt == qt);
        bf16_t* pw = &Pl[w * 16 * PPAD];

        #pragma unroll
        for (int f = 0; f < 2; ++f) {
            f32x4 accS[4];
            #pragma unroll
            for (int n = 0; n < 4; ++n) {
                f32x4 acc = (f32x4){0.f, 0.f, 0.f, 0.f};
                #pragma unroll
                for (int s = 0; s < 4; ++s) {
                    bf16x8 bk = *(const bf16x8*)(&Kl[(n * 16 + l16) * KPAD + s * 32 + l4 * 8]);
                    acc = __builtin_amdgcn_mfma_f32_16x16x32_bf16(aq[f][s], bk, acc, 0, 0, 0);
                }
                accS[n] = acc;
            }

            const int qrow_loc = rh + f * 16 + l4 * 4;
            float pm[4];
            #pragma unroll
            for (int j = 0; j < 4; ++j) pm[j] = -1e30f;
            #pragma unroll
            for (int n = 0; n < 4; ++n) {
                #pragma unroll
                for (int j = 0; j < 4; ++j) {
                    float sv = accS[n][j] * ATT_SCALE;
                    if (diag && (n * 16 + l16 > qrow_loc + j)) sv = -1e30f;
                    accS[n][j] = sv;
                    pm[j] = fmaxf(pm[j], sv);
                }
            }
            #pragma unroll
            for (int j = 0; j < 4; ++j) {
                float m0 = pm[j];
                m0 = fmaxf(m0, __shfl_xor(m0, 1));
                m0 = fmaxf(m0, __shfl_xor(m0, 2));
                m0 = fmaxf(m0, __shfl_xor(m0, 4));
                m0 = fmaxf(m0, __shfl_xor(m0, 8));
                pm[j] = m0;
            }
            float al[4], rs[4];
            #pragma unroll
            for (int j = 0; j < 4; ++j) {
                float mnew = fmaxf(mrun[f][j], pm[j]);
                al[j] = __expf(mrun[f][j] - mnew);
                mrun[f][j] = mnew;
                rs[j] = 0.f;
            }
            #pragma unroll
            for (int n = 0; n < 4; ++n) {
                #pragma unroll
                for (int j = 0; j < 4; ++j) {
                    float p = __expf(accS[n][j] - mrun[f][j]);
                    accS[n][j] = p;
                    rs[j] += p;
                }
            }
            #pragma unroll
            for (int j = 0; j < 4; ++j) {
                float r = rs[j];
                r += __shfl_xor(r, 1);
                r += __shfl_xor(r, 2);
                r += __shfl_xor(r, 4);
                r += __shfl_xor(r, 8);
                lsum[f][j] = lsum[f][j] * al[j] + r;
            }
            #pragma unroll
            for (int n = 0; n < 8; ++n) {
                #pragma unroll
                for (int j = 0; j < 4; ++j) accO[f][n][j] *= al[j];
            }
            #pragma unroll
            for (int n = 0; n < 4; ++n) {
                #pragma unroll
                for (int j = 0; j < 4; ++j)
                    pw[(l4 * 4 + j) * PPAD + n * 16 + l16] = (bf16_t)accS[n][j];
            }
            asm volatile("s_waitcnt lgkmcnt(0)" ::: "memory");
            __builtin_amdgcn_sched_barrier(0);
            #pragma unroll
            for (int ks = 0; ks < 2; ++ks) {
                bf16x8 ap = *(const bf16x8*)(&pw[l16 * PPAD + ks * 32 + l4 * 8]);
                #pragma unroll
                for (int n = 0; n < 8; ++n) {
                    int d   = n * 16 + l16;
                    int blk = (ks * 4 + l4) ^ ((d >> 3) & 7);
                    bf16x8 bv = *(const bf16x8*)(&Vt[d * VPAD + blk * 8]);
                    accO[f][n] = __builtin_amdgcn_mfma_f32_16x16x32_bf16(ap, bv, accO[f][n], 0, 0, 0);
                }
            }
        }
    }

    #pragma unroll
    for (int f = 0; f < 2; ++f) {
        #pragma unroll
        for (int j = 0; j < 4; ++j) {
            float inv = 1.f / lsum[f][j];
            float* op = og + (qtok0 + rh + f * 16 + l4 * 4 + j) * QD + h * HDIM;
            #pragma unroll
            for (int n = 0; n < 8; ++n)
                op[n * 16 + l16] = accO[f][n][j] * inv;
        }
    }
}

extern "C" void kernel_launch(void* const* d_in, const int* in_sizes, int n_in,
                              void* d_out, int out_size, void* d_ws, size_t ws_size,
                              hipStream_t stream) {
    const float* q = (const float*)d_in[0];
    const float* k = (const float*)d_in[1];
    const float* v = (const float*)d_in[2];
    float* o = (float*)d_out;

    const size_t kws_elems = (size_t)TOTAL * KVD;            // 8,388,608
    const size_t vws_elems = (size_t)BATCH * NKV * HDIM * SEQ;
    const size_t need = (kws_elems + vws_elems) * sizeof(bf16_t);  // 33.5 MB

    if (ws_size >= need) {
        bf16_t* kws  = (bf16_t*)d_ws;
        bf16_t* vtws = kws + kws_elems;
        attn_prepass_kernel<<<1536, 256, 0, stream>>>(k, v, kws, vtws);
        attn_fwd_v5<<<512, 1024, 0, stream>>>(q, kws, vtws, o);
    } else {
        attn_fwd_v1<<<NQT * BATCH * NKV, 512, 0, stream>>>(q, k, v, o);
    }
}

// Round 7
// 175.504 us; speedup vs baseline: 1.0159x; 1.0159x over previous
//
#include <hip/hip_runtime.h>
#include <hip/hip_bf16.h>
#include <stdint.h>

typedef __bf16 bf16_t;
typedef __attribute__((ext_vector_type(8))) __bf16 bf16x8;
typedef __attribute__((ext_vector_type(4))) __bf16 bf16x4;
typedef __attribute__((ext_vector_type(4))) float f32x4;
typedef __attribute__((ext_vector_type(16))) float f32x16;

#define NHEADS 32
#define HDIM 128
#define NKV 8
#define GQ 4
#define BATCH 8
#define SEQ 1024
#define TOTAL (BATCH * SEQ)
#define QD (NHEADS * HDIM)   // 4096
#define KVD (NKV * HDIM)     // 1024
#define ATT_SCALE 0.08838834764831845f
// scale * log2(e): fold into Q so QK^T directly yields exp2 argument.
#define QSCL (0.08838834764831845f * 1.4426950408889634f)

#define QBLK 64
#define KBLK 64
#define NQT (SEQ / QBLK)     // 16

__device__ __forceinline__ void gload16(const bf16_t* g, bf16_t* l) {
    __builtin_amdgcn_global_load_lds(
        (const __attribute__((address_space(1))) void*)g,
        (__attribute__((address_space(3))) void*)l,
        16, 0, 0);
}

__device__ __forceinline__ f32x16 zero16() {
    f32x16 z;
    #pragma unroll
    for (int j = 0; j < 16; ++j) z[j] = 0.f;
    return z;
}

// ===========================================================================
// Pre-pass: K fp32 -> bf16 (same layout); V fp32 -> bf16 TRANSPOSED
// Vt_ws[((b*8+hk)*128 + d)*1024 + tok].
// ===========================================================================
__global__ __launch_bounds__(256)
void attn_prepass_kernel(const float* __restrict__ kg, const float* __restrict__ vg,
                         bf16_t* __restrict__ kws, bf16_t* __restrict__ vtws)
{
    const int bid = blockIdx.x;
    const int tid = threadIdx.x;
    if (bid < 512) {
        __shared__ bf16_t Lt[128 * 130];   // [d][tok], pad 130
        const int b  = bid >> 6;
        const int hk = (bid >> 3) & 7;
        const int tt = bid & 7;
        const float* vp = vg + ((long)(b * SEQ + tt * 128)) * KVD + hk * HDIM;
        #pragma unroll
        for (int it = 0; it < 16; ++it) {
            int idx = it * 256 + tid;
            int t  = idx >> 5;
            int c4 = (idx & 31) * 4;
            float4 f = *(const float4*)(vp + (long)t * KVD + c4);
            Lt[(c4 + 0) * 130 + t] = (bf16_t)f.x;
            Lt[(c4 + 1) * 130 + t] = (bf16_t)f.y;
            Lt[(c4 + 2) * 130 + t] = (bf16_t)f.z;
            Lt[(c4 + 3) * 130 + t] = (bf16_t)f.w;
        }
        __syncthreads();
        bf16_t* op = vtws + ((long)((b * NKV + hk) * HDIM)) * SEQ + tt * 128;
        #pragma unroll
        for (int jt = 0; jt < 8; ++jt) {
            int jdx = jt * 256 + tid;
            int d  = jdx >> 4;
            int c8 = (jdx & 15) * 8;
            const bf16_t* lp = &Lt[d * 130 + c8];
            uint32_t u0 = *(const uint32_t*)(lp + 0);
            uint32_t u1 = *(const uint32_t*)(lp + 2);
            uint32_t u2 = *(const uint32_t*)(lp + 4);
            uint32_t u3 = *(const uint32_t*)(lp + 6);
            uint4 o; o.x = u0; o.y = u1; o.z = u2; o.w = u3;
            *(uint4*)(op + (long)d * SEQ + c8) = o;
        }
    } else {
        const long total4 = (long)TOTAL * KVD / 4;
        const float4* k4 = (const float4*)kg;
        for (long i = (long)(bid - 512) * 256 + tid; i < total4; i += 1024L * 256) {
            float4 f = k4[i];
            bf16x4 o4;
            o4[0] = (bf16_t)f.x; o4[1] = (bf16_t)f.y;
            o4[2] = (bf16_t)f.z; o4[3] = (bf16_t)f.w;
            *(bf16x4*)(kws + i * 4) = o4;
        }
    }
}

// ===========================================================================
// Main attention kernel (v6): 32x32x16 MFMA, 8 waves x 32 q-rows.
// r6 diagnosis: LDS read BW is the limiter (16 waves x full K/V tile re-read
// ~570KB/tile/CU); occupancy doubling (r6) changed nothing. 32-row waves
// halve the K/V B-operand re-reads (~300KB/tile). Keeps: gload_lds dbuf +
// vmcnt(4), XOR swizzle, slim softmax (exp2, no max), balanced pairing.
// 32x32 C/D layout (m74/m101 verified): col=lane&31, row=(reg&3)+8*(reg>>2)
// +4*(lane>>5). A/B loaded with the same k-slot convention (permutation
// cancels in the contraction).
// ===========================================================================
__global__ __launch_bounds__(512, 2)
void attn_fwd_v6(const float* __restrict__ qg, const bf16_t* __restrict__ kws,
                 const bf16_t* __restrict__ vtws, float* __restrict__ og)
{
    __shared__ __align__(16) bf16_t Kl[2][KBLK * HDIM];   // [64][128] rows 256B
    __shared__ __align__(16) bf16_t Vl[2][HDIM * KBLK];   // [128][64] rows 128B
    __shared__ __align__(16) bf16_t Pl[8][32 * 64];       // per-wave [32][64] rows 128B

    const int tid  = threadIdx.x;
    const int w    = tid >> 6;    // 0..7
    const int lane = tid & 63;
    const int l31  = lane & 31;
    const int l2   = lane >> 5;   // 0..1

    const int bid = blockIdx.x;   // 0..511
    const int bh  = bid & 63;
    const int pi  = bid >> 6;     // 0..7
    const int b   = bh >> 3;
    const int hk  = bh & 7;
    const int g   = w >> 1;       // head within kv group
    const int half = w & 1;
    const int rh  = half * 32;    // 32-row slot within the 64-row q-tile
    const int h   = hk * GQ + g;

    const bf16_t* kbase = kws + (long)(b * SEQ) * KVD + hk * HDIM;
    const bf16_t* vbase = vtws + (long)((b * NKV + hk) * HDIM) * SEQ;
    const int kc0 = w * 2;   // this wave's 2 chunks (of 16) per tile per buffer

    auto issue_tile = [&](int buf, int kt) {
        #pragma unroll
        for (int i = 0; i < 2; ++i) {
            int c = kc0 + i;
            int r = c * 4 + (lane >> 4);
            const bf16_t* gp = kbase + (long)(kt * KBLK + r) * KVD + (((lane & 15) ^ (r & 7)) * 8);
            gload16(gp, &Kl[buf][c * 512]);
        }
        #pragma unroll
        for (int i = 0; i < 2; ++i) {
            int c = kc0 + i;
            int d = c * 8 + (lane >> 3);
            const bf16_t* gp = vbase + (long)d * SEQ + kt * KBLK + (((lane & 7) ^ (d & 7)) * 8);
            gload16(gp, &Vl[buf][c * 512]);
        }
    };

    for (int ph = 0; ph < 2; ++ph) {
        const int qt = ph ? pi : (NQT - 1 - pi);   // heavy q-tile first, then light
        const long qtok0 = (long)b * SEQ + qt * QBLK;

        // ---- Q fragments (A-op): row = l31, d = s*16 + l2*8 + e; pre-scaled ----
        bf16x8 aq[8];
        {
            const float* qp = qg + (qtok0 + rh + l31) * QD + h * HDIM + l2 * 8;
            #pragma unroll
            for (int s = 0; s < 8; ++s) {
                float4 x = *(const float4*)(qp + s * 16);
                float4 y = *(const float4*)(qp + s * 16 + 4);
                bf16x8 t;
                t[0] = (bf16_t)(x.x * QSCL); t[1] = (bf16_t)(x.y * QSCL);
                t[2] = (bf16_t)(x.z * QSCL); t[3] = (bf16_t)(x.w * QSCL);
                t[4] = (bf16_t)(y.x * QSCL); t[5] = (bf16_t)(y.y * QSCL);
                t[6] = (bf16_t)(y.z * QSCL); t[7] = (bf16_t)(y.w * QSCL);
                aq[s] = t;
            }
        }
        __builtin_amdgcn_sched_barrier(0);

        f32x16 accO[4];
        #pragma unroll
        for (int n = 0; n < 4; ++n) accO[n] = zero16();
        float rsum[16];
        #pragma unroll
        for (int r = 0; r < 16; ++r) rsum[r] = 0.f;

        const int nkt = qt + 1;
        issue_tile(0, 0);
        if (nkt > 1) issue_tile(1, 1);

        for (int kt = 0; kt < nkt; ++kt) {
            const int cur = kt & 1;
            if (kt + 1 < nkt) asm volatile("s_waitcnt vmcnt(4)" ::: "memory");
            else              asm volatile("s_waitcnt vmcnt(0)" ::: "memory");
            __builtin_amdgcn_s_barrier();
            __builtin_amdgcn_sched_barrier(0);

            const bool diag  = (kt == qt);
            const bool skip1 = diag && (rh == 0);   // cols 32-63 fully masked
            bf16_t* pw = &Pl[w][0];
            const bf16_t* Kc = &Kl[cur][0];
            const bf16_t* Vc = &Vl[cur][0];

            // ---- S' = (Q*scl) K^T : D col(k-col)=n*32+l31, rows via C/D map ----
            f32x16 accS[2];
            __builtin_amdgcn_s_setprio(1);
            {
                f32x16 acc = zero16();
                #pragma unroll
                for (int s = 0; s < 8; ++s) {
                    int elem = (s * 16 + l2 * 8) ^ ((l31 & 7) << 3);
                    bf16x8 bk = *(const bf16x8*)(Kc + l31 * 128 + elem);
                    acc = __builtin_amdgcn_mfma_f32_32x32x16_bf16(aq[s], bk, acc, 0, 0, 0);
                }
                accS[0] = acc;
            }
            if (!skip1) {
                f32x16 acc = zero16();
                #pragma unroll
                for (int s = 0; s < 8; ++s) {
                    int elem = (s * 16 + l2 * 8) ^ ((l31 & 7) << 3);
                    bf16x8 bk = *(const bf16x8*)(Kc + (32 + l31) * 128 + elem);
                    acc = __builtin_amdgcn_mfma_f32_32x32x16_bf16(aq[s], bk, acc, 0, 0, 0);
                }
                accS[1] = acc;
            } else {
                accS[1] = zero16();
            }
            __builtin_amdgcn_s_setprio(0);

            // ---- slim softmax: p = exp2(S'), zero masked, accumulate rsum ----
            const int qb = rh + 4 * l2;   // + rowoff(r)
            #pragma unroll
            for (int r = 0; r < 16; ++r) {
                const int rowoff = (r & 3) + 8 * (r >> 2);
                float p = exp2f(accS[0][r]);
                if (diag && (l31 > qb + rowoff)) p = 0.f;
                accS[0][r] = p;
                rsum[r] += p;
            }
            if (!skip1) {
                #pragma unroll
                for (int r = 0; r < 16; ++r) {
                    const int rowoff = (r & 3) + 8 * (r >> 2);
                    float p = exp2f(accS[1][r]);
                    if (diag && (32 + l31 > qb + rowoff)) p = 0.f;
                    accS[1][r] = p;
                    rsum[r] += p;
                }
            }

            // ---- P -> per-wave LDS [32][64], XOR-swizzled ----
            #pragma unroll
            for (int n = 0; n < 2; ++n) {
                #pragma unroll
                for (int r = 0; r < 16; ++r) {
                    const int row = (r & 3) + 8 * (r >> 2) + 4 * l2;
                    const int col = n * 32 + l31;
                    pw[row * 64 + (col ^ ((row & 7) << 3))] = (bf16_t)accS[n][r];
                }
            }
            asm volatile("s_waitcnt lgkmcnt(0)" ::: "memory");
            __builtin_amdgcn_sched_barrier(0);

            // ---- O += P V : A row=l31 (P row), B col=l31 (V d-col) ----
            __builtin_amdgcn_s_setprio(1);
            bf16x8 pa[4];
            #pragma unroll
            for (int ks = 0; ks < 4; ++ks) {
                int elem = (ks * 16 + l2 * 8) ^ ((l31 & 7) << 3);
                pa[ks] = *(const bf16x8*)(pw + l31 * 64 + elem);
            }
            #pragma unroll
            for (int n = 0; n < 4; ++n) {
                #pragma unroll
                for (int ks = 0; ks < 4; ++ks) {
                    int elem = (ks * 16 + l2 * 8) ^ ((l31 & 7) << 3);
                    bf16x8 bv = *(const bf16x8*)(Vc + (n * 32 + l31) * 64 + elem);
                    accO[n] = __builtin_amdgcn_mfma_f32_32x32x16_bf16(pa[ks], bv, accO[n], 0, 0, 0);
                }
            }
            __builtin_amdgcn_s_setprio(0);

            __builtin_amdgcn_sched_barrier(0);
            __builtin_amdgcn_s_barrier();
            if (kt + 2 < nkt) issue_tile(cur, kt + 2);
        }

        // ---- epilogue: reduce rsum across 32 cols, normalize, store ----
        #pragma unroll
        for (int r = 0; r < 16; ++r) {
            const int rowoff = (r & 3) + 8 * (r >> 2);
            float s = rsum[r];
            s += __shfl_xor(s, 1);
            s += __shfl_xor(s, 2);
            s += __shfl_xor(s, 4);
            s += __shfl_xor(s, 8);
            s += __shfl_xor(s, 16);
            float inv = 1.f / s;
            float* op = og + (qtok0 + rh + rowoff + 4 * l2) * QD + h * HDIM + l31;
            #pragma unroll
            for (int n = 0; n < 4; ++n)
                op[n * 32] = accO[n][r] * inv;
        }
    }
}

// ===========================================================================
// Fallback (round-1 kernel) if ws is too small for the bf16 pre-pass.
// ===========================================================================
#define KPAD 136
#define VPAD 72
#define PPAD 72
__global__ __launch_bounds__(512, 2)
void attn_fwd_v1(const float* __restrict__ qg, const float* __restrict__ kg,
                 const float* __restrict__ vg, float* __restrict__ og)
{
    __shared__ bf16_t Kl[KBLK * KPAD];
    __shared__ bf16_t Vt[HDIM * VPAD];
    __shared__ bf16_t Pl[8 * 16 * PPAD];

    const int tid  = threadIdx.x;
    const int w    = tid >> 6;
    const int lane = tid & 63;
    const int l4   = lane >> 4;
    const int l16  = lane & 15;

    const int bid = blockIdx.x;
    const int bh  = bid % 64;
    const int qt  = (NQT - 1) - bid / 64;
    const int b   = bh / NKV;
    const int hk  = bh % NKV;
    const int g   = w >> 1;
    const int h   = hk * GQ + g;
    const int rh  = (w & 1) * 32;

    const long qtok0 = (long)b * SEQ + qt * QBLK;

    bf16x8 aq[2][4];
    #pragma unroll
    for (int f = 0; f < 2; ++f) {
        const float* qp = qg + (qtok0 + rh + f * 16 + l16) * QD + h * HDIM + l4 * 8;
        #pragma unroll
        for (int s = 0; s < 4; ++s) {
            float4 x = *(const float4*)(qp + s * 32);
            float4 y = *(const float4*)(qp + s * 32 + 4);
            bf16x8 t;
            t[0] = (bf16_t)x.x; t[1] = (bf16_t)x.y; t[2] = (bf16_t)x.z; t[3] = (bf16_t)x.w;
            t[4] = (bf16_t)y.x; t[5] = (bf16_t)y.y; t[6] = (bf16_t)y.z; t[7] = (bf16_t)y.w;
            aq[f][s] = t;
        }
    }

    f32x4 accO[2][8];
    float mrun[2][4], lsum[2][4];
    #pragma unroll
    for (int f = 0; f < 2; ++f) {
        #pragma unroll
        for (int n = 0; n < 8; ++n) accO[f][n] = (f32x4){0.f, 0.f, 0.f, 0.f};
        #pragma unroll
        for (int j = 0; j < 4; ++j) { mrun[f][j] = -1e30f; lsum[f][j] = 0.f; }
    }

    const long ktok0 = (long)b * SEQ;
    const int nkt = qt + 1;

    for (int kt = 0; kt < nkt; ++kt) {
        __syncthreads();
        const float* kp = kg + (ktok0 + kt * KBLK) * KVD + hk * HDIM;
        const float* vp = vg + (ktok0 + kt * KBLK) * KVD + hk * HDIM;
        #pragma unroll
        for (int it = 0; it < 4; ++it) {
            int idx = it * 512 + tid;
            int row = idx >> 5;
            int c4  = (idx & 31) * 4;
            float4 kf = *(const float4*)(kp + (long)row * KVD + c4);
            bf16x4 k4;
            k4[0] = (bf16_t)kf.x; k4[1] = (bf16_t)kf.y; k4[2] = (bf16_t)kf.z; k4[3] = (bf16_t)kf.w;
            *(bf16x4*)(&Kl[row * KPAD + c4]) = k4;
            float4 vf = *(const float4*)(vp + (long)row * KVD + c4);
            const float* vfa = (const float*)&vf;
            #pragma unroll
            for (int m = 0; m < 4; ++m) {
                int d   = c4 + m;
                int blk = (row >> 3) ^ ((d >> 3) & 7);
                Vt[d * VPAD + blk * 8 + (row & 7)] = (bf16_t)vfa[m];
            }
        }
        __syncthreads();

        const bool diag = (kt == qt);
        bf16_t* pw = &Pl[w * 16 * PPAD];

        #pragma unroll
        for (int f = 0; f < 2; ++f) {
            f32x4 accS[4];
            #pragma unroll
            for (int n = 0; n < 4; ++n) {
                f32x4 acc = (f32x4){0.f, 0.f, 0.f, 0.f};
                #pragma unroll
                for (int s = 0; s < 4; ++s) {
                    bf16x8 bk = *(const bf16x8*)(&Kl[(n * 16 + l16) * KPAD + s * 32 + l4 * 8]);
                    acc = __builtin_amdgcn_mfma_f32_16x16x32_bf16(aq[f][s], bk, acc, 0, 0, 0);
                }
                accS[n] = acc;
            }

            const int qrow_loc = rh + f * 16 + l4 * 4;
            float pm[4];
            #pragma unroll
            for (int j = 0; j < 4; ++j) pm[j] = -1e30f;
            #pragma unroll
            for (int n = 0; n < 4; ++n) {
                #pragma unroll
                for (int j = 0; j < 4; ++j) {
                    float sv = accS[n][j] * ATT_SCALE;
                    if (diag && (n * 16 + l16 > qrow_loc + j)) sv = -1e30f;
                    accS[n][j] = sv;
                    pm[j] = fmaxf(pm[j], sv);
                }
            }
            #pragma unroll
            for (int j = 0; j < 4; ++j) {
                float m0 = pm[j];
                m0 = fmaxf(m0, __shfl_xor(m0, 1));
                m0 = fmaxf(m0, __shfl_xor(m0, 2));
                m0 = fmaxf(m0, __shfl_xor(m0, 4));
                m0 = fmaxf(m0, __shfl_xor(m0, 8));
                pm[j] = m0;
            }
            float al[4], rs[4];
            #pragma unroll
            for (int j = 0; j < 4; ++j) {
                float mnew = fmaxf(mrun[f][j], pm[j]);
                al[j] = __expf(mrun[f][j] - mnew);
                mrun[f][j] = mnew;
                rs[j] = 0.f;
            }
            #pragma unroll
            for (int n = 0; n < 4; ++n) {
                #pragma unroll
                for (int j = 0; j < 4; ++j) {
                    float p = __expf(accS[n][j] - mrun[f][j]);
                    accS[n][j] = p;
                    rs[j] += p;
                }
            }
            #pragma unroll
            for (int j = 0; j < 4; ++j) {
                float r = rs[j];
                r += __shfl_xor(r, 1);
                r += __shfl_xor(r, 2);
                r += __shfl_xor(r, 4);
                r += __shfl_xor(r, 8);
                lsum[f][j] = lsum[f][j] * al[j] + r;
            }
            #pragma unroll
            for (int n = 0; n < 8; ++n) {
                #pragma unroll
                for (int j = 0; j < 4; ++j) accO[f][n][j] *= al[j];
            }
            #pragma unroll
            for (int n = 0; n < 4; ++n) {
                #pragma unroll
                for (int j = 0; j < 4; ++j)
                    pw[(l4 * 4 + j) * PPAD + n * 16 + l16] = (bf16_t)accS[n][j];
            }
            asm volatile("s_waitcnt lgkmcnt(0)" ::: "memory");
            __builtin_amdgcn_sched_barrier(0);
            #pragma unroll
            for (int ks = 0; ks < 2; ++ks) {
                bf16x8 ap = *(const bf16x8*)(&pw[l16 * PPAD + ks * 32 + l4 * 8]);
                #pragma unroll
                for (int n = 0; n < 8; ++n) {
                    int d   = n * 16 + l16;
                    int blk = (ks * 4 + l4) ^ ((d >> 3) & 7);
                    bf16x8 bv = *(const bf16x8*)(&Vt[d * VPAD + blk * 8]);
                    accO[f][n] = __builtin_amdgcn_mfma_f32_16x16x32_bf16(ap, bv, accO[f][n], 0, 0, 0);
                }
            }
        }
    }

    #pragma unroll
    for (int f = 0; f < 2; ++f) {
        #pragma unroll
        for (int j = 0; j < 4; ++j) {
            float inv = 1.f / lsum[f][j];
            float* op = og + (qtok0 + rh + f * 16 + l4 * 4 + j) * QD + h * HDIM;
            #pragma unroll
            for (int n = 0; n < 8; ++n)
                op[n * 16 + l16] = accO[f][n][j] * inv;
        }
    }
}

extern "C" void kernel_launch(void* const* d_in, const int* in_sizes, int n_in,
                              void* d_out, int out_size, void* d_ws, size_t ws_size,
                              hipStream_t stream) {
    const float* q = (const float*)d_in[0];
    const float* k = (const float*)d_in[1];
    const float* v = (const float*)d_in[2];
    float* o = (float*)d_out;

    const size_t kws_elems = (size_t)TOTAL * KVD;            // 8,388,608
    const size_t vws_elems = (size_t)BATCH * NKV * HDIM * SEQ;
    const size_t need = (kws_elems + vws_elems) * sizeof(bf16_t);  // 33.5 MB

    if (ws_size >= need) {
        bf16_t* kws  = (bf16_t*)d_ws;
        bf16_t* vtws = kws + kws_elems;
        attn_prepass_kernel<<<1536, 256, 0, stream>>>(k, v, kws, vtws);
        attn_fwd_v6<<<512, 512, 0, stream>>>(q, kws, vtws, o);
    } else {
        attn_fwd_v1<<<NQT * BATCH * NKV, 512, 0, stream>>>(q, k, v, o);
    }
}

// Round 9
// 159.435 us; speedup vs baseline: 1.1183x; 1.1008x over previous
//
#include <hip/hip_runtime.h>
#include <hip/hip_bf16.h>
#include <stdint.h>

typedef __bf16 bf16_t;
typedef __attribute__((ext_vector_type(8))) __bf16 bf16x8;
typedef __attribute__((ext_vector_type(4))) __bf16 bf16x4;
typedef __attribute__((ext_vector_type(4))) float f32x4;
typedef __attribute__((ext_vector_type(16))) float f32x16;

#define NHEADS 32
#define HDIM 128
#define NKV 8
#define GQ 4
#define BATCH 8
#define SEQ 1024
#define TOTAL (BATCH * SEQ)
#define QD (NHEADS * HDIM)   // 4096
#define KVD (NKV * HDIM)     // 1024
#define ATT_SCALE 0.08838834764831845f
#define QSCL (0.08838834764831845f * 1.4426950408889634f)

#define QBLK 64
#define KBLK 64
#define NQT (SEQ / QBLK)     // 16

__device__ __forceinline__ void gload16(const bf16_t* g, bf16_t* l) {
    __builtin_amdgcn_global_load_lds(
        (const __attribute__((address_space(1))) void*)g,
        (__attribute__((address_space(3))) void*)l,
        16, 0, 0);
}

__device__ __forceinline__ f32x16 zero16() {
    f32x16 z;
    #pragma unroll
    for (int j = 0; j < 16; ++j) z[j] = 0.f;
    return z;
}

// proven in m214v22: pack two f32 -> one u32 of 2 bf16 (lo = src0, hi = src1)
__device__ __forceinline__ uint32_t cvt_pk_bf16(float lo, float hi) {
    uint32_t r;
    asm("v_cvt_pk_bf16_f32 %0, %1, %2" : "=v"(r) : "v"(lo), "v"(hi));
    return r;
}

// Pack a lane's 16 softmaxed P values (C/D layout of swapped QK^T: value r has
// kloc = (r&3)+8*(r>>2)+4*l2, all for q-row = lane&31) into two PV A-fragments
// (k = ks*16 + 8*l2 + e). Cross-half exchange via shfl_xor(32) (hazard-safe,
// semantics exact) + per-lane selects — replaces r8's raw permlane asm (the
// suspected corruption: unknown swap direction + missing hazard waits).
__device__ __forceinline__ void pack_pa(const f32x16 &t, int l2, bf16x8 &pe, bf16x8 &po) {
    uint32_t c[8], s[8];
    #pragma unroll
    for (int j = 0; j < 8; ++j) c[j] = cvt_pk_bf16(t[2 * j], t[2 * j + 1]);
    #pragma unroll
    for (int j = 0; j < 8; ++j) s[j] = (uint32_t)__shfl_xor((int)c[j], 32);
    union { uint32_t u[4]; bf16x8 v; } a, b;
    a.u[0] = l2 ? s[2] : c[0];
    a.u[1] = l2 ? s[3] : c[1];
    a.u[2] = l2 ? c[2] : s[0];
    a.u[3] = l2 ? c[3] : s[1];
    b.u[0] = l2 ? s[6] : c[4];
    b.u[1] = l2 ? s[7] : c[5];
    b.u[2] = l2 ? c[6] : s[4];
    b.u[3] = l2 ? c[7] : s[5];
    pe = a.v; po = b.v;
}

// ===========================================================================
// Pre-pass: K fp32 -> bf16 (same layout); V fp32 -> bf16 TRANSPOSED
// ===========================================================================
__global__ __launch_bounds__(256)
void attn_prepass_kernel(const float* __restrict__ kg, const float* __restrict__ vg,
                         bf16_t* __restrict__ kws, bf16_t* __restrict__ vtws)
{
    const int bid = blockIdx.x;
    const int tid = threadIdx.x;
    if (bid < 512) {
        __shared__ bf16_t Lt[128 * 130];
        const int b  = bid >> 6;
        const int hk = (bid >> 3) & 7;
        const int tt = bid & 7;
        const float* vp = vg + ((long)(b * SEQ + tt * 128)) * KVD + hk * HDIM;
        #pragma unroll
        for (int it = 0; it < 16; ++it) {
            int idx = it * 256 + tid;
            int t  = idx >> 5;
            int c4 = (idx & 31) * 4;
            float4 f = *(const float4*)(vp + (long)t * KVD + c4);
            Lt[(c4 + 0) * 130 + t] = (bf16_t)f.x;
            Lt[(c4 + 1) * 130 + t] = (bf16_t)f.y;
            Lt[(c4 + 2) * 130 + t] = (bf16_t)f.z;
            Lt[(c4 + 3) * 130 + t] = (bf16_t)f.w;
        }
        __syncthreads();
        bf16_t* op = vtws + ((long)((b * NKV + hk) * HDIM)) * SEQ + tt * 128;
        #pragma unroll
        for (int jt = 0; jt < 8; ++jt) {
            int jdx = jt * 256 + tid;
            int d  = jdx >> 4;
            int c8 = (jdx & 15) * 8;
            const bf16_t* lp = &Lt[d * 130 + c8];
            uint32_t u0 = *(const uint32_t*)(lp + 0);
            uint32_t u1 = *(const uint32_t*)(lp + 2);
            uint32_t u2 = *(const uint32_t*)(lp + 4);
            uint32_t u3 = *(const uint32_t*)(lp + 6);
            uint4 o; o.x = u0; o.y = u1; o.z = u2; o.w = u3;
            *(uint4*)(op + (long)d * SEQ + c8) = o;
        }
    } else {
        const long total4 = (long)TOTAL * KVD / 4;
        const float4* k4 = (const float4*)kg;
        for (long i = (long)(bid - 512) * 256 + tid; i < total4; i += 1024L * 256) {
            float4 f = k4[i];
            bf16x4 o4;
            o4[0] = (bf16_t)f.x; o4[1] = (bf16_t)f.y;
            o4[2] = (bf16_t)f.z; o4[3] = (bf16_t)f.w;
            *(bf16x4*)(kws + i * 4) = o4;
        }
    }
}

// ===========================================================================
// Main attention kernel (v8): r8's swapped-QK in-register softmax, with the
// cross-half P exchange done via shfl_xor(32) (not raw permlane asm) and
// exp2f (not raw v_exp asm). Structure:
//   mfma(A=K, B=Q) -> lane holds P[kloc][qrow=lane&31] in regs; softmax,
//   cvt_pk pack, shfl_xor exchange -> PV A-frags; P never touches LDS.
//   3-deep K/V buffers, ONE barrier per tile (issue kt+2 into buf (kt-1)%3
//   right after the barrier; its readers all passed this barrier).
// ===========================================================================
__global__ __launch_bounds__(512, 2)
void attn_fwd_v8(const float* __restrict__ qg, const bf16_t* __restrict__ kws,
                 const bf16_t* __restrict__ vtws, float* __restrict__ og)
{
    __shared__ __align__(16) bf16_t Kl[3][KBLK * HDIM];   // [64][128] rows 256B
    __shared__ __align__(16) bf16_t Vl[3][HDIM * KBLK];   // [128][64] rows 128B

    const int tid  = threadIdx.x;
    const int w    = tid >> 6;    // 0..7
    const int lane = tid & 63;
    const int l31  = lane & 31;
    const int l2   = lane >> 5;   // 0..1
    const int kl2  = 4 * l2;

    const int bid = blockIdx.x;   // 0..511
    const int bh  = bid & 63;
    const int pi  = bid >> 6;     // 0..7
    const int b   = bh >> 3;
    const int hk  = bh & 7;
    const int g   = w >> 1;       // head within kv group
    const int rh  = (w & 1) * 32; // 32-row slot within the 64-row q-tile
    const int h   = hk * GQ + g;
    const int qrow_loc = rh + l31;

    const bf16_t* kbase = kws + (long)(b * SEQ) * KVD + hk * HDIM;
    const bf16_t* vbase = vtws + (long)((b * NKV + hk) * HDIM) * SEQ;
    const int kc0 = w * 2;

    auto issue_tile = [&](int buf, int kt) {
        #pragma unroll
        for (int i = 0; i < 2; ++i) {
            int c = kc0 + i;
            int r = c * 4 + (lane >> 4);
            const bf16_t* gp = kbase + (long)(kt * KBLK + r) * KVD + (((lane & 15) ^ (r & 7)) * 8);
            gload16(gp, &Kl[buf][c * 512]);
        }
        #pragma unroll
        for (int i = 0; i < 2; ++i) {
            int c = kc0 + i;
            int d = c * 8 + (lane >> 3);
            const bf16_t* gp = vbase + (long)d * SEQ + kt * KBLK + (((lane & 7) ^ (d & 7)) * 8);
            gload16(gp, &Vl[buf][c * 512]);
        }
    };

    for (int ph = 0; ph < 2; ++ph) {
        const int qt = ph ? pi : (NQT - 1 - pi);   // heavy q-tile first, then light
        const long qtok0 = (long)b * SEQ + qt * QBLK;

        // ---- Q fragments (B-op): col = l31 (q-row), k-slots d = s*16+l2*8+e ----
        bf16x8 aq[8];
        {
            const float* qp = qg + (qtok0 + rh + l31) * QD + h * HDIM + l2 * 8;
            #pragma unroll
            for (int s = 0; s < 8; ++s) {
                float4 x = *(const float4*)(qp + s * 16);
                float4 y = *(const float4*)(qp + s * 16 + 4);
                bf16x8 t;
                t[0] = (bf16_t)(x.x * QSCL); t[1] = (bf16_t)(x.y * QSCL);
                t[2] = (bf16_t)(x.z * QSCL); t[3] = (bf16_t)(x.w * QSCL);
                t[4] = (bf16_t)(y.x * QSCL); t[5] = (bf16_t)(y.y * QSCL);
                t[6] = (bf16_t)(y.z * QSCL); t[7] = (bf16_t)(y.w * QSCL);
                aq[s] = t;
            }
        }
        __builtin_amdgcn_sched_barrier(0);
        // Phase boundary: all waves done reading previous phase's buffers.
        __syncthreads();

        f32x16 accO[4];
        #pragma unroll
        for (int n = 0; n < 4; ++n) accO[n] = zero16();
        float rsum = 0.f;

        const int nkt = qt + 1;
        issue_tile(0, 0);
        if (nkt > 1) issue_tile(1, 1);

        for (int kt = 0; kt < nkt; ++kt) {
            const bf16_t* Kc = &Kl[kt % 3][0];
            const bf16_t* Vc = &Vl[kt % 3][0];
            if (kt + 1 < nkt) asm volatile("s_waitcnt vmcnt(4)" ::: "memory");
            else              asm volatile("s_waitcnt vmcnt(0)" ::: "memory");
            __builtin_amdgcn_s_barrier();
            if (kt + 2 < nkt) issue_tile((kt + 2) % 3, kt + 2);
            __builtin_amdgcn_sched_barrier(0);

            const bool diag  = (kt == qt);
            const bool skip1 = diag && (rh == 0);   // k-cols 32-63 fully masked

            bf16x8 pa[4];

            // ---- T = K Q^T (kb=0, k-cols 0..31) ----
            f32x16 accT0 = zero16();
            __builtin_amdgcn_s_setprio(1);
            #pragma unroll
            for (int s = 0; s < 8; ++s) {
                int elem = (s * 16 + l2 * 8) ^ ((l31 & 7) << 3);
                bf16x8 bk = *(const bf16x8*)(Kc + l31 * 128 + elem);
                accT0 = __builtin_amdgcn_mfma_f32_32x32x16_bf16(bk, aq[s], accT0, 0, 0, 0);
            }
            __builtin_amdgcn_s_setprio(0);
            #pragma unroll
            for (int r = 0; r < 16; ++r) {
                const int kloc = (r & 3) + 8 * (r >> 2) + kl2;
                float p = exp2f(accT0[r]);
                if (diag && (kloc > qrow_loc)) p = 0.f;
                accT0[r] = p;
                rsum += p;
            }
            pack_pa(accT0, l2, pa[0], pa[1]);

            if (!skip1) {
                // ---- kb=1: k-cols 32..63 ----
                f32x16 accT1 = zero16();
                __builtin_amdgcn_s_setprio(1);
                #pragma unroll
                for (int s = 0; s < 8; ++s) {
                    int elem = (s * 16 + l2 * 8) ^ ((l31 & 7) << 3);
                    bf16x8 bk = *(const bf16x8*)(Kc + (32 + l31) * 128 + elem);
                    accT1 = __builtin_amdgcn_mfma_f32_32x32x16_bf16(bk, aq[s], accT1, 0, 0, 0);
                }
                __builtin_amdgcn_s_setprio(0);
                #pragma unroll
                for (int r = 0; r < 16; ++r) {
                    const int kloc = 32 + (r & 3) + 8 * (r >> 2) + kl2;
                    float p = exp2f(accT1[r]);
                    if (diag && (kloc > qrow_loc)) p = 0.f;
                    accT1[r] = p;
                    rsum += p;
                }
                pack_pa(accT1, l2, pa[2], pa[3]);
            } else {
                union { uint32_t u[4]; bf16x8 v; } zz;
                zz.u[0] = zz.u[1] = zz.u[2] = zz.u[3] = 0;
                pa[2] = zz.v; pa[3] = zz.v;
            }

            // ---- O += P V : A = pa (in-reg), B = Vt from LDS ----
            __builtin_amdgcn_s_setprio(1);
            #pragma unroll
            for (int n = 0; n < 4; ++n) {
                #pragma unroll
                for (int ks = 0; ks < 4; ++ks) {
                    int elem = (ks * 16 + l2 * 8) ^ ((l31 & 7) << 3);
                    bf16x8 bv = *(const bf16x8*)(Vc + (n * 32 + l31) * 64 + elem);
                    accO[n] = __builtin_amdgcn_mfma_f32_32x32x16_bf16(pa[ks], bv, accO[n], 0, 0, 0);
                }
            }
            __builtin_amdgcn_s_setprio(0);
        }

        // ---- epilogue: rsum lives at lane(q-row); redistribute to C/D rows ----
        rsum += __shfl_xor(rsum, 32);
        float inv = 1.f / rsum;
        #pragma unroll
        for (int r = 0; r < 16; ++r) {
            const int qr = (r & 3) + 8 * (r >> 2) + kl2;
            float invr = __shfl(inv, qr);
            float* op = og + (qtok0 + rh + qr) * QD + h * HDIM + l31;
            #pragma unroll
            for (int n = 0; n < 4; ++n)
                op[n * 32] = accO[n][r] * invr;
        }
    }
}

// ===========================================================================
// Fallback (round-1 kernel) if ws is too small for the bf16 pre-pass.
// ===========================================================================
#define KPAD 136
#define VPAD 72
#define PPAD 72
__global__ __launch_bounds__(512, 2)
void attn_fwd_v1(const float* __restrict__ qg, const float* __restrict__ kg,
                 const float* __restrict__ vg, float* __restrict__ og)
{
    __shared__ bf16_t Kl[KBLK * KPAD];
    __shared__ bf16_t Vt[HDIM * VPAD];
    __shared__ bf16_t Pl[8 * 16 * PPAD];

    const int tid  = threadIdx.x;
    const int w    = tid >> 6;
    const int lane = tid & 63;
    const int l4   = lane >> 4;
    const int l16  = lane & 15;

    const int bid = blockIdx.x;
    const int bh  = bid % 64;
    const int qt  = (NQT - 1) - bid / 64;
    const int b   = bh / NKV;
    const int hk  = bh % NKV;
    const int g   = w >> 1;
    const int h   = hk * GQ + g;
    const int rh  = (w & 1) * 32;

    const long qtok0 = (long)b * SEQ + qt * QBLK;

    bf16x8 aq[2][4];
    #pragma unroll
    for (int f = 0; f < 2; ++f) {
        const float* qp = qg + (qtok0 + rh + f * 16 + l16) * QD + h * HDIM + l4 * 8;
        #pragma unroll
        for (int s = 0; s < 4; ++s) {
            float4 x = *(const float4*)(qp + s * 32);
            float4 y = *(const float4*)(qp + s * 32 + 4);
            bf16x8 t;
            t[0] = (bf16_t)x.x; t[1] = (bf16_t)x.y; t[2] = (bf16_t)x.z; t[3] = (bf16_t)x.w;
            t[4] = (bf16_t)y.x; t[5] = (bf16_t)y.y; t[6] = (bf16_t)y.z; t[7] = (bf16_t)y.w;
            aq[f][s] = t;
        }
    }

    f32x4 accO[2][8];
    float mrun[2][4], lsum[2][4];
    #pragma unroll
    for (int f = 0; f < 2; ++f) {
        #pragma unroll
        for (int n = 0; n < 8; ++n) accO[f][n] = (f32x4){0.f, 0.f, 0.f, 0.f};
        #pragma unroll
        for (int j = 0; j < 4; ++j) { mrun[f][j] = -1e30f; lsum[f][j] = 0.f; }
    }

    const long ktok0 = (long)b * SEQ;
    const int nkt = qt + 1;

    for (int kt = 0; kt < nkt; ++kt) {
        __syncthreads();
        const float* kp = kg + (ktok0 + kt * KBLK) * KVD + hk * HDIM;
        const float* vp = vg + (ktok0 + kt * KBLK) * KVD + hk * HDIM;
        #pragma unroll
        for (int it = 0; it < 4; ++it) {
            int idx = it * 512 + tid;
            int row = idx >> 5;
            int c4  = (idx & 31) * 4;
            float4 kf = *(const float4*)(kp + (long)row * KVD + c4);
            bf16x4 k4;
            k4[0] = (bf16_t)kf.x; k4[1] = (bf16_t)kf.y; k4[2] = (bf16_t)kf.z; k4[3] = (bf16_t)kf.w;
            *(bf16x4*)(&Kl[row * KPAD + c4]) = k4;
            float4 vf = *(const float4*)(vp + (long)row * KVD + c4);
            const float* vfa = (const float*)&vf;
            #pragma unroll
            for (int m = 0; m < 4; ++m) {
                int d   = c4 + m;
                int blk = (row >> 3) ^ ((d >> 3) & 7);
                Vt[d * VPAD + blk * 8 + (row & 7)] = (bf16_t)vfa[m];
            }
        }
        __syncthreads();

        const bool diag = (kt == qt);
        bf16_t* pw = &Pl[w * 16 * PPAD];

        #pragma unroll
        for (int f = 0; f < 2; ++f) {
            f32x4 accS[4];
            #pragma unroll
            for (int n = 0; n < 4; ++n) {
                f32x4 acc = (f32x4){0.f, 0.f, 0.f, 0.f};
                #pragma unroll
                for (int s = 0; s < 4; ++s) {
                    bf16x8 bk = *(const bf16x8*)(&Kl[(n * 16 + l16) * KPAD + s * 32 + l4 * 8]);
                    acc = __builtin_amdgcn_mfma_f32_16x16x32_bf16(aq[f][s], bk, acc, 0, 0, 0);
                }
                accS[n] = acc;
            }

            const int qrow_loc = rh + f * 16 + l4 * 4;
            float pm[4];
            #pragma unroll
            for (int j = 0; j < 4; ++j) pm[j] = -1e30f;
            #pragma unroll
            for (int n = 0; n < 4; ++n) {
                #pragma unroll
                for (int j = 0; j < 4; ++j) {
                    float sv = accS[n][j] * ATT_SCALE;
                    if (diag && (n * 16 + l16 > qrow_loc + j)) sv = -1e30f;
                    accS[n][j] = sv;
                    pm[j] = fmaxf(pm[j], sv);
                }
            }
            #pragma unroll
            for (int j = 0; j < 4; ++j) {
                float m0 = pm[j];
                m0 = fmaxf(m0, __shfl_xor(m0, 1));
                m0 = fmaxf(m0, __shfl_xor(m0, 2));
                m0 = fmaxf(m0, __shfl_xor(m0, 4));
                m0 = fmaxf(m0, __shfl_xor(m0, 8));
                pm[j] = m0;
            }
            float al[4], rs[4];
            #pragma unroll
            for (int j = 0; j < 4; ++j) {
                float mnew = fmaxf(mrun[f][j], pm[j]);
                al[j] = __expf(mrun[f][j] - mnew);
                mrun[f][j] = mnew;
                rs[j] = 0.f;
            }
            #pragma unroll
            for (int n = 0; n < 4; ++n) {
                #pragma unroll
                for (int j = 0; j < 4; ++j) {
                    float p = __expf(accS[n][j] - mrun[f][j]);
                    accS[n][j] = p;
                    rs[j] += p;
                }
            }
            #pragma unroll
            for (int j = 0; j < 4; ++j) {
                float r = rs[j];
                r += __shfl_xor(r, 1);
                r += __shfl_xor(r, 2);
                r += __shfl_xor(r, 4);
                r += __shfl_xor(r, 8);
                lsum[f][j] = lsum[f][j] * al[j] + r;
            }
            #pragma unroll
            for (int n = 0; n < 8; ++n) {
                #pragma unroll
                for (int j = 0; j < 4; ++j) accO[f][n][j] *= al[j];
            }
            #pragma unroll
            for (int n = 0; n < 4; ++n) {
                #pragma unroll
                for (int j = 0; j < 4; ++j)
                    pw[(l4 * 4 + j) * PPAD + n * 16 + l16] = (bf16_t)accS[n][j];
            }
            asm volatile("s_waitcnt lgkmcnt(0)" ::: "memory");
            __builtin_amdgcn_sched_barrier(0);
            #pragma unroll
            for (int ks = 0; ks < 2; ++ks) {
                bf16x8 ap = *(const bf16x8*)(&pw[l16 * PPAD + ks * 32 + l4 * 8]);
                #pragma unroll
                for (int n = 0; n < 8; ++n) {
                    int d   = n * 16 + l16;
                    int blk = (ks * 4 + l4) ^ ((d >> 3) & 7);
                    bf16x8 bv = *(const bf16x8*)(&Vt[d * VPAD + blk * 8]);
                    accO[f][n] = __builtin_amdgcn_mfma_f32_16x16x32_bf16(ap, bv, accO[f][n], 0, 0, 0);
                }
            }
        }
    }

    #pragma unroll
    for (int f = 0; f < 2; ++f) {
        #pragma unroll
        for (int j = 0; j < 4; ++j) {
            float inv = 1.f / lsum[f][j];
            float* op = og + (qtok0 + rh + f * 16 + l4 * 4 + j) * QD + h * HDIM;
            #pragma unroll
            for (int n = 0; n < 8; ++n)
                op[n * 16 + l16] = accO[f][n][j] * inv;
        }
    }
}

extern "C" void kernel_launch(void* const* d_in, const int* in_sizes, int n_in,
                              void* d_out, int out_size, void* d_ws, size_t ws_size,
                              hipStream_t stream) {
    const float* q = (const float*)d_in[0];
    const float* k = (const float*)d_in[1];
    const float* v = (const float*)d_in[2];
    float* o = (float*)d_out;

    const size_t kws_elems = (size_t)TOTAL * KVD;            // 8,388,608
    const size_t vws_elems = (size_t)BATCH * NKV * HDIM * SEQ;
    const size_t need = (kws_elems + vws_elems) * sizeof(bf16_t);  // 33.5 MB

    if (ws_size >= need) {
        bf16_t* kws  = (bf16_t*)d_ws;
        bf16_t* vtws = kws + kws_elems;
        attn_prepass_kernel<<<1536, 256, 0, stream>>>(k, v, kws, vtws);
        attn_fwd_v8<<<512, 512, 0, stream>>>(q, kws, vtws, o);
    } else {
        attn_fwd_v1<<<NQT * BATCH * NKV, 512, 0, stream>>>(q, k, v, o);
    }
}

// Round 11
// 151.532 us; speedup vs baseline: 1.1766x; 1.0522x over previous
//
#include <hip/hip_runtime.h>
#include <hip/hip_bf16.h>
#include <stdint.h>

typedef __bf16 bf16_t;
typedef __attribute__((ext_vector_type(8))) __bf16 bf16x8;
typedef __attribute__((ext_vector_type(4))) __bf16 bf16x4;
typedef __attribute__((ext_vector_type(4))) float f32x4;

#define NHEADS 32
#define HDIM 128
#define NKV 8
#define GQ 4
#define BATCH 8
#define SEQ 1024
#define TOTAL (BATCH * SEQ)
#define QD (NHEADS * HDIM)   // 4096
#define KVD (NKV * HDIM)     // 1024
#define ATT_SCALE 0.08838834764831845f
#define QSCL (0.08838834764831845f * 1.4426950408889634f)

#define QBLK 64
#define KBLK 64
#define NQT (SEQ / QBLK)     // 16

__device__ __forceinline__ void gload16(const bf16_t* g, bf16_t* l) {
    __builtin_amdgcn_global_load_lds(
        (const __attribute__((address_space(1))) void*)g,
        (__attribute__((address_space(3))) void*)l,
        16, 0, 0);
}

// proven in m214v22 / v8: pack two f32 -> u32 of 2 bf16 (lo = src0, hi = src1)
__device__ __forceinline__ uint32_t cvt_pk_bf16(float lo, float hi) {
    uint32_t r;
    asm("v_cvt_pk_bf16_f32 %0, %1, %2" : "=v"(r) : "v"(lo), "v"(hi));
    return r;
}

// ===========================================================================
// Pre-pass: K fp32 -> bf16 (same layout); V fp32 -> bf16 TRANSPOSED with
// k-column PERMUTATION within each 64-token block:
//   k = (k5 k4 k3 k2 k1 k0) -> pos = k5<<5 | k3<<4 | k2<<3 | k4<<2 | k1 k0
// This makes the PV B-fragment (read at chunk ks*4+l4) match the k's that a
// lane naturally holds in-register after the swapped QK^T (kb = 2ks+{0,1},
// j = 0..3) -> the P->A pack needs ZERO cross-lane ops (r10 bug: the shfl
// select was evaluated in the source lane -> swapped kb on half the lanes).
// ===========================================================================
__global__ __launch_bounds__(256)
void attn_prepass_kernel(const float* __restrict__ kg, const float* __restrict__ vg,
                         bf16_t* __restrict__ kws, bf16_t* __restrict__ vtws)
{
    const int bid = blockIdx.x;
    const int tid = threadIdx.x;
    if (bid < 512) {
        __shared__ bf16_t Lt[128 * 130];
        const int b  = bid >> 6;
        const int hk = (bid >> 3) & 7;
        const int tt = bid & 7;
        const float* vp = vg + ((long)(b * SEQ + tt * 128)) * KVD + hk * HDIM;
        #pragma unroll
        for (int it = 0; it < 16; ++it) {
            int idx = it * 256 + tid;
            int t  = idx >> 5;
            int c4 = (idx & 31) * 4;
            float4 f = *(const float4*)(vp + (long)t * KVD + c4);
            Lt[(c4 + 0) * 130 + t] = (bf16_t)f.x;
            Lt[(c4 + 1) * 130 + t] = (bf16_t)f.y;
            Lt[(c4 + 2) * 130 + t] = (bf16_t)f.z;
            Lt[(c4 + 3) * 130 + t] = (bf16_t)f.w;
        }
        __syncthreads();
        bf16_t* op = vtws + ((long)((b * NKV + hk) * HDIM)) * SEQ + tt * 128;
        #pragma unroll
        for (int jt = 0; jt < 8; ++jt) {
            int jdx = jt * 256 + tid;
            int d  = jdx >> 4;          // 0..127
            int c8 = (jdx & 15) * 8;    // 0..120 (8-aligned)
            const bf16_t* lp = &Lt[d * 130 + c8];
            uint32_t u0 = *(const uint32_t*)(lp + 0);
            uint32_t u1 = *(const uint32_t*)(lp + 2);
            uint32_t u2 = *(const uint32_t*)(lp + 4);
            uint32_t u3 = *(const uint32_t*)(lp + 6);
            // chunk base kl0 (bits k5,k4,k3) -> pos base p0 = k5<<5|k3<<4|k4<<2
            int kl0 = c8 & 63;
            int p0  = (kl0 & 32) | ((kl0 & 8) << 1) | ((kl0 & 16) >> 2);
            bf16_t* dst = op + (long)d * SEQ + (c8 & ~63);
            uint2 lo; lo.x = u0; lo.y = u1;     // k2=0: j=0..3
            uint2 hi; hi.x = u2; hi.y = u3;     // k2=1: j=0..3
            *(uint2*)(dst + p0)     = lo;
            *(uint2*)(dst + p0 + 8) = hi;
        }
    } else {
        const long total4 = (long)TOTAL * KVD / 4;
        const float4* k4 = (const float4*)kg;
        for (long i = (long)(bid - 512) * 256 + tid; i < total4; i += 1024L * 256) {
            float4 f = k4[i];
            bf16x4 o4;
            o4[0] = (bf16_t)f.x; o4[1] = (bf16_t)f.y;
            o4[2] = (bf16_t)f.z; o4[3] = (bf16_t)f.w;
            *(bf16x4*)(kws + i * 4) = o4;
        }
    }
}

// ===========================================================================
// Main attention kernel (v10): v9 (2 independent blocks/CU target) with the
// P->A pack done ENTIRELY IN-LANE (V k-columns pre-permuted in the prepass).
//   - swapped QK^T: mfma(A=K, B=Q) -> lane(l4,l16) holds P[k=kb*16+l4*4+j]
//     [q=l16] for kb=0..3; slim softmax in-register.
//   - pa[ks] = {u[2ks][0],u[2ks][1],u[2ks+1][0],u[2ks+1][1]} (no shuffles);
//     B-side k mapping matches by construction of the V permutation.
//   - LDS 64KB (2-deep K/V), launch_bounds(512,4) -> 128-reg cap, ~110 used
//     -> 2 blocks/CU. Spill tripwire: WRITE_SIZE >> 131MB.
//   - gload_lds staging + counted vmcnt, XOR swizzle, balanced pairing,
//     per-wave diag sub-block skip.
// ===========================================================================
__global__ __launch_bounds__(512, 4)
void attn_fwd_v10(const float* __restrict__ qg, const bf16_t* __restrict__ kws,
                  const bf16_t* __restrict__ vtws, float* __restrict__ og)
{
    __shared__ __align__(16) bf16_t Kl[2][KBLK * HDIM];   // 2 x 16KB, [64][128]
    __shared__ __align__(16) bf16_t Vl[2][HDIM * KBLK];   // 2 x 16KB, [128][64]

    const int tid  = threadIdx.x;
    const int w    = tid >> 6;    // 0..7
    const int lane = tid & 63;
    const int l16  = lane & 15;
    const int l4   = lane >> 4;   // 0..3

    const int bid = blockIdx.x;        // 0..1023
    const int hg  = bid & 1;           // head-pair within kv group
    const int bh  = (bid >> 1) & 63;
    const int pi  = bid >> 7;          // 0..7
    const int b   = bh >> 3;
    const int hk  = bh & 7;
    const int g2  = w >> 2;            // head within pair
    const int fs  = w & 3;             // 16-row slot in 64-row q-tile
    const int h   = hk * GQ + hg * 2 + g2;

    const bf16_t* kbase = kws + (long)(b * SEQ) * KVD + hk * HDIM;
    const bf16_t* vbase = vtws + (long)((b * NKV + hk) * HDIM) * SEQ;
    const int kc0 = w * 2;

    auto issue_tile = [&](int buf, int kt) {
        #pragma unroll
        for (int i = 0; i < 2; ++i) {
            int c = kc0 + i;
            int r = c * 4 + (lane >> 4);
            const bf16_t* gp = kbase + (long)(kt * KBLK + r) * KVD + (((lane & 15) ^ (r & 7)) * 8);
            gload16(gp, &Kl[buf][c * 512]);
        }
        #pragma unroll
        for (int i = 0; i < 2; ++i) {
            int c = kc0 + i;
            int d = c * 8 + (lane >> 3);
            const bf16_t* gp = vbase + (long)d * SEQ + kt * KBLK + (((lane & 7) ^ (d & 7)) * 8);
            gload16(gp, &Vl[buf][c * 512]);
        }
    };

    for (int ph = 0; ph < 2; ++ph) {
        const int qt = ph ? pi : (NQT - 1 - pi);   // heavy q-tile first
        const long qtok0 = (long)b * SEQ + qt * QBLK;

        // ---- Q fragments (B-op): col = l16 (q-row), k-slots d = s*32+l4*8+e ----
        bf16x8 aq[4];
        {
            const float* qp = qg + (qtok0 + fs * 16 + l16) * QD + h * HDIM + l4 * 8;
            #pragma unroll
            for (int s = 0; s < 4; ++s) {
                float4 x = *(const float4*)(qp + s * 32);
                float4 y = *(const float4*)(qp + s * 32 + 4);
                bf16x8 t;
                t[0] = (bf16_t)(x.x * QSCL); t[1] = (bf16_t)(x.y * QSCL);
                t[2] = (bf16_t)(x.z * QSCL); t[3] = (bf16_t)(x.w * QSCL);
                t[4] = (bf16_t)(y.x * QSCL); t[5] = (bf16_t)(y.y * QSCL);
                t[6] = (bf16_t)(y.z * QSCL); t[7] = (bf16_t)(y.w * QSCL);
                aq[s] = t;
            }
        }
        __builtin_amdgcn_sched_barrier(0);
        __syncthreads();   // phase boundary: prev phase's LDS reads done

        f32x4 accO[8];
        #pragma unroll
        for (int n = 0; n < 8; ++n) accO[n] = (f32x4){0.f, 0.f, 0.f, 0.f};
        float rsum = 0.f;

        const int nkt = qt + 1;
        issue_tile(0, 0);
        if (nkt > 1) issue_tile(1, 1);

        for (int kt = 0; kt < nkt; ++kt) {
            const bf16_t* Kc = &Kl[kt & 1][0];
            const bf16_t* Vc = &Vl[kt & 1][0];
            if (kt + 1 < nkt) asm volatile("s_waitcnt vmcnt(4)" ::: "memory");
            else              asm volatile("s_waitcnt vmcnt(0)" ::: "memory");
            __builtin_amdgcn_s_barrier();
            __builtin_amdgcn_sched_barrier(0);

            const bool diag = (kt == qt);

            // ---- T = K Q^T per 16-col sub-block; in-reg softmax; cvt_pk ----
            uint32_t u[4][2];
            #pragma unroll
            for (int kb = 0; kb < 4; ++kb) { u[kb][0] = 0; u[kb][1] = 0; }

            #pragma unroll
            for (int kb = 0; kb < 4; ++kb) {
                const bool skip = diag && (kb > fs);
                if (!skip) {
                    f32x4 t = (f32x4){0.f, 0.f, 0.f, 0.f};
                    __builtin_amdgcn_s_setprio(1);
                    #pragma unroll
                    for (int s = 0; s < 4; ++s) {
                        int elem = (s * 32 + l4 * 8) ^ ((l16 & 7) << 3);
                        bf16x8 bk = *(const bf16x8*)(Kc + (kb * 16 + l16) * 128 + elem);
                        t = __builtin_amdgcn_mfma_f32_16x16x32_bf16(bk, aq[s], t, 0, 0, 0);
                    }
                    __builtin_amdgcn_s_setprio(0);
                    const bool needmask = diag && (kb == fs);
                    #pragma unroll
                    for (int j = 0; j < 4; ++j) {
                        float p = exp2f(t[j]);
                        if (needmask && (kb * 16 + l4 * 4 + j > fs * 16 + l16)) p = 0.f;
                        t[j] = p;
                        rsum += p;
                    }
                    u[kb][0] = cvt_pk_bf16(t[0], t[1]);
                    u[kb][1] = cvt_pk_bf16(t[2], t[3]);
                }
            }

            // ---- P -> PV A-frags: IN-LANE (V k-perm makes B match) ----
            bf16x8 pa[2];
            #pragma unroll
            for (int ks = 0; ks < 2; ++ks) {
                union { uint32_t uu[4]; bf16x8 v; } pk;
                pk.uu[0] = u[ks * 2][0];
                pk.uu[1] = u[ks * 2][1];
                pk.uu[2] = u[ks * 2 + 1][0];
                pk.uu[3] = u[ks * 2 + 1][1];
                pa[ks] = pk.v;
            }

            // ---- O += P V ----
            __builtin_amdgcn_s_setprio(1);
            #pragma unroll
            for (int n = 0; n < 8; ++n) {
                #pragma unroll
                for (int ks = 0; ks < 2; ++ks) {
                    int elem = (ks * 32 + l4 * 8) ^ ((l16 & 7) << 3);
                    bf16x8 bv = *(const bf16x8*)(Vc + (n * 16 + l16) * 64 + elem);
                    accO[n] = __builtin_amdgcn_mfma_f32_16x16x32_bf16(pa[ks], bv, accO[n], 0, 0, 0);
                }
            }
            __builtin_amdgcn_s_setprio(0);

            __builtin_amdgcn_sched_barrier(0);
            __builtin_amdgcn_s_barrier();   // all reads of buf kt&1 done
            if (kt + 2 < nkt) issue_tile(kt & 1, kt + 2);
        }

        // ---- epilogue: reduce rsum over l4 group, normalize, store ----
        rsum += __shfl_xor(rsum, 16);
        rsum += __shfl_xor(rsum, 32);
        float inv = 1.f / rsum;   // valid for q-row = l16 on every lane
        #pragma unroll
        for (int j = 0; j < 4; ++j) {
            const int qr = l4 * 4 + j;
            float invr = __shfl(inv, qr);   // lane qr holds q-row qr's inv
            float* op = og + (qtok0 + fs * 16 + qr) * QD + h * HDIM + l16;
            #pragma unroll
            for (int n = 0; n < 8; ++n)
                op[n * 16] = accO[n][j] * invr;
        }
    }
}

// ===========================================================================
// Fallback (round-1 kernel) if ws is too small for the bf16 pre-pass.
// ===========================================================================
#define KPAD 136
#define VPAD 72
#define PPAD 72
__global__ __launch_bounds__(512, 2)
void attn_fwd_v1(const float* __restrict__ qg, const float* __restrict__ kg,
                 const float* __restrict__ vg, float* __restrict__ og)
{
    __shared__ bf16_t Kl[KBLK * KPAD];
    __shared__ bf16_t Vt[HDIM * VPAD];
    __shared__ bf16_t Pl[8 * 16 * PPAD];

    const int tid  = threadIdx.x;
    const int w    = tid >> 6;
    const int lane = tid & 63;
    const int l4   = lane >> 4;
    const int l16  = lane & 15;

    const int bid = blockIdx.x;
    const int bh  = bid % 64;
    const int qt  = (NQT - 1) - bid / 64;
    const int b   = bh / NKV;
    const int hk  = bh % NKV;
    const int g   = w >> 1;
    const int h   = hk * GQ + g;
    const int rh  = (w & 1) * 32;

    const long qtok0 = (long)b * SEQ + qt * QBLK;

    bf16x8 aq[2][4];
    #pragma unroll
    for (int f = 0; f < 2; ++f) {
        const float* qp = qg + (qtok0 + rh + f * 16 + l16) * QD + h * HDIM + l4 * 8;
        #pragma unroll
        for (int s = 0; s < 4; ++s) {
            float4 x = *(const float4*)(qp + s * 32);
            float4 y = *(const float4*)(qp + s * 32 + 4);
            bf16x8 t;
            t[0] = (bf16_t)x.x; t[1] = (bf16_t)x.y; t[2] = (bf16_t)x.z; t[3] = (bf16_t)x.w;
            t[4] = (bf16_t)y.x; t[5] = (bf16_t)y.y; t[6] = (bf16_t)y.z; t[7] = (bf16_t)y.w;
            aq[f][s] = t;
        }
    }

    f32x4 accO[2][8];
    float mrun[2][4], lsum[2][4];
    #pragma unroll
    for (int f = 0; f < 2; ++f) {
        #pragma unroll
        for (int n = 0; n < 8; ++n) accO[f][n] = (f32x4){0.f, 0.f, 0.f, 0.f};
        #pragma unroll
        for (int j = 0; j < 4; ++j) { mrun[f][j] = -1e30f; lsum[f][j] = 0.f; }
    }

    const long ktok0 = (long)b * SEQ;
    const int nkt = qt + 1;

    for (int kt = 0; kt < nkt; ++kt) {
        __syncthreads();
        const float* kp = kg + (ktok0 + kt * KBLK) * KVD + hk * HDIM;
        const float* vp = vg + (ktok0 + kt * KBLK) * KVD + hk * HDIM;
        #pragma unroll
        for (int it = 0; it < 4; ++it) {
            int idx = it * 512 + tid;
            int row = idx >> 5;
            int c4  = (idx & 31) * 4;
            float4 kf = *(const float4*)(kp + (long)row * KVD + c4);
            bf16x4 k4;
            k4[0] = (bf16_t)kf.x; k4[1] = (bf16_t)kf.y; k4[2] = (bf16_t)kf.z; k4[3] = (bf16_t)kf.w;
            *(bf16x4*)(&Kl[row * KPAD + c4]) = k4;
            float4 vf = *(const float4*)(vp + (long)row * KVD + c4);
            const float* vfa = (const float*)&vf;
            #pragma unroll
            for (int m = 0; m < 4; ++m) {
                int d   = c4 + m;
                int blk = (row >> 3) ^ ((d >> 3) & 7);
                Vt[d * VPAD + blk * 8 + (row & 7)] = (bf16_t)vfa[m];
            }
        }
        __syncthreads();

        const bool diag = (kt == qt);
        bf16_t* pw = &Pl[w * 16 * PPAD];

        #pragma unroll
        for (int f = 0; f < 2; ++f) {
            f32x4 accS[4];
            #pragma unroll
            for (int n = 0; n < 4; ++n) {
                f32x4 acc = (f32x4){0.f, 0.f, 0.f, 0.f};
                #pragma unroll
                for (int s = 0; s < 4; ++s) {
                    bf16x8 bk = *(const bf16x8*)(&Kl[(n * 16 + l16) * KPAD + s * 32 + l4 * 8]);
                    acc = __builtin_amdgcn_mfma_f32_16x16x32_bf16(aq[f][s], bk, acc, 0, 0, 0);
                }
                accS[n] = acc;
            }

            const int qrow_loc = rh + f * 16 + l4 * 4;
            float pm[4];
            #pragma unroll
            for (int j = 0; j < 4; ++j) pm[j] = -1e30f;
            #pragma unroll
            for (int n = 0; n < 4; ++n) {
                #pragma unroll
                for (int j = 0; j < 4; ++j) {
                    float sv = accS[n][j] * ATT_SCALE;
                    if (diag && (n * 16 + l16 > qrow_loc + j)) sv = -1e30f;
                    accS[n][j] = sv;
                    pm[j] = fmaxf(pm[j], sv);
                }
            }
            #pragma unroll
            for (int j = 0; j < 4; ++j) {
                float m0 = pm[j];
                m0 = fmaxf(m0, __shfl_xor(m0, 1));
                m0 = fmaxf(m0, __shfl_xor(m0, 2));
                m0 = fmaxf(m0, __shfl_xor(m0, 4));
                m0 = fmaxf(m0, __shfl_xor(m0, 8));
                pm[j] = m0;
            }
            float al[4], rs[4];
            #pragma unroll
            for (int j = 0; j < 4; ++j) {
                float mnew = fmaxf(mrun[f][j], pm[j]);
                al[j] = __expf(mrun[f][j] - mnew);
                mrun[f][j] = mnew;
                rs[j] = 0.f;
            }
            #pragma unroll
            for (int n = 0; n < 4; ++n) {
                #pragma unroll
                for (int j = 0; j < 4; ++j) {
                    float p = __expf(accS[n][j] - mrun[f][j]);
                    accS[n][j] = p;
                    rs[j] += p;
                }
            }
            #pragma unroll
            for (int j = 0; j < 4; ++j) {
                float r = rs[j];
                r += __shfl_xor(r, 1);
                r += __shfl_xor(r, 2);
                r += __shfl_xor(r, 4);
                r += __shfl_xor(r, 8);
                lsum[f][j] = lsum[f][j] * al[j] + r;
            }
            #pragma unroll
            for (int n = 0; n < 8; ++n) {
                #pragma unroll
                for (int j = 0; j < 4; ++j) accO[f][n][j] *= al[j];
            }
            #pragma unroll
            for (int n = 0; n < 4; ++n) {
                #pragma unroll
                for (int j = 0; j < 4; ++j)
                    pw[(l4 * 4 + j) * PPAD + n * 16 + l16] = (bf16_t)accS[n][j];
            }
            asm volatile("s_waitcnt lgkmcnt(0)" ::: "memory");
            __builtin_amdgcn_sched_barrier(0);
            #pragma unroll
            for (int ks = 0; ks < 2; ++ks) {
                bf16x8 ap = *(const bf16x8*)(&pw[l16 * PPAD + ks * 32 + l4 * 8]);
                #pragma unroll
                for (int n = 0; n < 8; ++n) {
                    int d   = n * 16 + l16;
                    int blk = (ks * 4 + l4) ^ ((d >> 3) & 7);
                    bf16x8 bv = *(const bf16x8*)(&Vt[d * VPAD + blk * 8]);
                    accO[f][n] = __builtin_amdgcn_mfma_f32_16x16x32_bf16(ap, bv, accO[f][n], 0, 0, 0);
                }
            }
        }
    }

    #pragma unroll
    for (int f = 0; f < 2; ++f) {
        #pragma unroll
        for (int j = 0; j < 4; ++j) {
            float inv = 1.f / lsum[f][j];
            float* op = og + (qtok0 + rh + f * 16 + l4 * 4 + j) * QD + h * HDIM;
            #pragma unroll
            for (int n = 0; n < 8; ++n)
                op[n * 16 + l16] = accO[f][n][j] * inv;
        }
    }
}

extern "C" void kernel_launch(void* const* d_in, const int* in_sizes, int n_in,
                              void* d_out, int out_size, void* d_ws, size_t ws_size,
                              hipStream_t stream) {
    const float* q = (const float*)d_in[0];
    const float* k = (const float*)d_in[1];
    const float* v = (const float*)d_in[2];
    float* o = (float*)d_out;

    const size_t kws_elems = (size_t)TOTAL * KVD;            // 8,388,608
    const size_t vws_elems = (size_t)BATCH * NKV * HDIM * SEQ;
    const size_t need = (kws_elems + vws_elems) * sizeof(bf16_t);  // 33.5 MB

    if (ws_size >= need) {
        bf16_t* kws  = (bf16_t*)d_ws;
        bf16_t* vtws = kws + kws_elems;
        attn_prepass_kernel<<<1536, 256, 0, stream>>>(k, v, kws, vtws);
        attn_fwd_v10<<<1024, 512, 0, stream>>>(q, kws, vtws, o);
    } else {
        attn_fwd_v1<<<NQT * BATCH * NKV, 512, 0, stream>>>(q, k, v, o);
    }
}

// Round 12
// 145.851 us; speedup vs baseline: 1.2225x; 1.0389x over previous
//
#include <hip/hip_runtime.h>
#include <hip/hip_bf16.h>
#include <stdint.h>

typedef __bf16 bf16_t;
typedef __attribute__((ext_vector_type(8))) __bf16 bf16x8;
typedef __attribute__((ext_vector_type(4))) __bf16 bf16x4;
typedef __attribute__((ext_vector_type(4))) float f32x4;

#define NHEADS 32
#define HDIM 128
#define NKV 8
#define GQ 4
#define BATCH 8
#define SEQ 1024
#define TOTAL (BATCH * SEQ)
#define QD (NHEADS * HDIM)   // 4096
#define KVD (NKV * HDIM)     // 1024
#define ATT_SCALE 0.08838834764831845f
#define QSCL (0.08838834764831845f * 1.4426950408889634f)

#define QBLK 64
#define KBLK 64
#define NQT (SEQ / QBLK)     // 16

__device__ __forceinline__ void gload16(const bf16_t* g, bf16_t* l) {
    __builtin_amdgcn_global_load_lds(
        (const __attribute__((address_space(1))) void*)g,
        (__attribute__((address_space(3))) void*)l,
        16, 0, 0);
}

// proven in m214v22 / v8: pack two f32 -> u32 of 2 bf16 (lo = src0, hi = src1)
__device__ __forceinline__ uint32_t cvt_pk_bf16(float lo, float hi) {
    uint32_t r;
    asm("v_cvt_pk_bf16_f32 %0, %1, %2" : "=v"(r) : "v"(lo), "v"(hi));
    return r;
}

// ===========================================================================
// Pre-pass: K fp32 -> bf16 (same layout); V fp32 -> bf16 TRANSPOSED with
// k-column PERMUTATION within each 64-token block:
//   k = (k5 k4 k3 k2 k1 k0) -> pos = k5<<5 | k3<<4 | k2<<3 | k4<<2 | k1 k0
// Makes the PV B-fragment (chunk ks*4+l4) match the k's a lane holds
// in-register after the swapped QK^T -> P->A pack is fully in-lane.
// ===========================================================================
__global__ __launch_bounds__(256)
void attn_prepass_kernel(const float* __restrict__ kg, const float* __restrict__ vg,
                         bf16_t* __restrict__ kws, bf16_t* __restrict__ vtws)
{
    const int bid = blockIdx.x;
    const int tid = threadIdx.x;
    if (bid < 512) {
        __shared__ bf16_t Lt[128 * 130];
        const int b  = bid >> 6;
        const int hk = (bid >> 3) & 7;
        const int tt = bid & 7;
        const float* vp = vg + ((long)(b * SEQ + tt * 128)) * KVD + hk * HDIM;
        #pragma unroll
        for (int it = 0; it < 16; ++it) {
            int idx = it * 256 + tid;
            int t  = idx >> 5;
            int c4 = (idx & 31) * 4;
            float4 f = *(const float4*)(vp + (long)t * KVD + c4);
            Lt[(c4 + 0) * 130 + t] = (bf16_t)f.x;
            Lt[(c4 + 1) * 130 + t] = (bf16_t)f.y;
            Lt[(c4 + 2) * 130 + t] = (bf16_t)f.z;
            Lt[(c4 + 3) * 130 + t] = (bf16_t)f.w;
        }
        __syncthreads();
        bf16_t* op = vtws + ((long)((b * NKV + hk) * HDIM)) * SEQ + tt * 128;
        #pragma unroll
        for (int jt = 0; jt < 8; ++jt) {
            int jdx = jt * 256 + tid;
            int d  = jdx >> 4;          // 0..127
            int c8 = (jdx & 15) * 8;    // 0..120 (8-aligned)
            const bf16_t* lp = &Lt[d * 130 + c8];
            uint32_t u0 = *(const uint32_t*)(lp + 0);
            uint32_t u1 = *(const uint32_t*)(lp + 2);
            uint32_t u2 = *(const uint32_t*)(lp + 4);
            uint32_t u3 = *(const uint32_t*)(lp + 6);
            // chunk base kl0 (bits k5,k4,k3) -> pos base p0 = k5<<5|k3<<4|k4<<2
            int kl0 = c8 & 63;
            int p0  = (kl0 & 32) | ((kl0 & 8) << 1) | ((kl0 & 16) >> 2);
            bf16_t* dst = op + (long)d * SEQ + (c8 & ~63);
            uint2 lo; lo.x = u0; lo.y = u1;     // k2=0: j=0..3
            uint2 hi; hi.x = u2; hi.y = u3;     // k2=1: j=0..3
            *(uint2*)(dst + p0)     = lo;
            *(uint2*)(dst + p0 + 8) = hi;
        }
    } else {
        const long total4 = (long)TOTAL * KVD / 4;
        const float4* k4 = (const float4*)kg;
        for (long i = (long)(bid - 512) * 256 + tid; i < total4; i += 1024L * 256) {
            float4 f = k4[i];
            bf16x4 o4;
            o4[0] = (bf16_t)f.x; o4[1] = (bf16_t)f.y;
            o4[2] = (bf16_t)f.z; o4[3] = (bf16_t)f.w;
            *(bf16x4*)(kws + i * 4) = o4;
        }
    }
}

// ===========================================================================
// Main attention kernel (v11): v10 + three serial/sync-cost cuts:
//   1. ONE barrier per tile (issue-1-ahead): at tile kt's top barrier all
//      waves finished reading buf[(kt+1)&1] (tile kt-1) -> issue kt+1 there
//      right after the barrier; no end-of-tile barrier. Per-wave vmcnt(0)
//      BEFORE the barrier preserves the staged-data visibility proof.
//   2. rsum as 4 partial accumulators (FP chain depth 16 -> 4; compiler
//      can't reassociate FP adds itself).
//   3. Staging addresses hoisted: per-lane tile-invariant offsets + two
//      walking pointers (strides KBLK*KVD, KBLK).
// Everything else identical to v10 (swapped QK^T in-reg softmax, in-lane
// pack via V k-perm, 2-deep gload_lds, XOR swizzle, balanced pairing,
// 2 heads/block, launch_bounds(512,4) -> 2 blocks/CU).
// ===========================================================================
__global__ __launch_bounds__(512, 4)
void attn_fwd_v11(const float* __restrict__ qg, const bf16_t* __restrict__ kws,
                  const bf16_t* __restrict__ vtws, float* __restrict__ og)
{
    __shared__ __align__(16) bf16_t Kl[2][KBLK * HDIM];   // 2 x 16KB, [64][128]
    __shared__ __align__(16) bf16_t Vl[2][HDIM * KBLK];   // 2 x 16KB, [128][64]

    const int tid  = threadIdx.x;
    const int w    = tid >> 6;    // 0..7
    const int lane = tid & 63;
    const int l16  = lane & 15;
    const int l4   = lane >> 4;   // 0..3

    const int bid = blockIdx.x;        // 0..1023
    const int hg  = bid & 1;           // head-pair within kv group
    const int bh  = (bid >> 1) & 63;
    const int pi  = bid >> 7;          // 0..7
    const int b   = bh >> 3;
    const int hk  = bh & 7;
    const int g2  = w >> 2;            // head within pair
    const int fs  = w & 3;             // 16-row slot in 64-row q-tile
    const int h   = hk * GQ + hg * 2 + g2;

    const bf16_t* kbase = kws + (long)(b * SEQ) * KVD + hk * HDIM;
    const bf16_t* vbase = vtws + (long)((b * NKV + hk) * HDIM) * SEQ;
    const int kc0 = w * 2;

    // ---- tile-invariant per-lane staging offsets (hoisted, change #3) ----
    long koff[2], voff[2];
    int ldst[2];
    #pragma unroll
    for (int i = 0; i < 2; ++i) {
        int c = kc0 + i;
        int r = c * 4 + (lane >> 4);
        koff[i] = (long)r * KVD + (((lane & 15) ^ (r & 7)) * 8);
        int d = c * 8 + (lane >> 3);
        voff[i] = (long)d * SEQ + (((lane & 7) ^ (d & 7)) * 8);
        ldst[i] = c * 512;
    }
    const long KT_STRIDE = (long)KBLK * KVD;   // 65536 elems

    for (int ph = 0; ph < 2; ++ph) {
        const int qt = ph ? pi : (NQT - 1 - pi);   // heavy q-tile first
        const long qtok0 = (long)b * SEQ + qt * QBLK;

        // ---- Q fragments (B-op): col = l16 (q-row), k-slots d = s*32+l4*8+e ----
        bf16x8 aq[4];
        {
            const float* qp = qg + (qtok0 + fs * 16 + l16) * QD + h * HDIM + l4 * 8;
            #pragma unroll
            for (int s = 0; s < 4; ++s) {
                float4 x = *(const float4*)(qp + s * 32);
                float4 y = *(const float4*)(qp + s * 32 + 4);
                bf16x8 t;
                t[0] = (bf16_t)(x.x * QSCL); t[1] = (bf16_t)(x.y * QSCL);
                t[2] = (bf16_t)(x.z * QSCL); t[3] = (bf16_t)(x.w * QSCL);
                t[4] = (bf16_t)(y.x * QSCL); t[5] = (bf16_t)(y.y * QSCL);
                t[6] = (bf16_t)(y.z * QSCL); t[7] = (bf16_t)(y.w * QSCL);
                aq[s] = t;
            }
        }
        __builtin_amdgcn_sched_barrier(0);
        __syncthreads();   // phase boundary: prev phase's LDS reads done

        f32x4 accO[8];
        #pragma unroll
        for (int n = 0; n < 8; ++n) accO[n] = (f32x4){0.f, 0.f, 0.f, 0.f};
        float rsum[4] = {0.f, 0.f, 0.f, 0.f};   // change #2: 4 partials

        const bf16_t* kn = kbase;
        const bf16_t* vn = vbase;
        auto issue_tile = [&](int buf) {
            gload16(kn + koff[0], &Kl[buf][ldst[0]]);
            gload16(kn + koff[1], &Kl[buf][ldst[1]]);
            gload16(vn + voff[0], &Vl[buf][ldst[0]]);
            gload16(vn + voff[1], &Vl[buf][ldst[1]]);
            kn += KT_STRIDE;
            vn += KBLK;
        };

        const int nkt = qt + 1;
        issue_tile(0);

        for (int kt = 0; kt < nkt; ++kt) {
            const bf16_t* Kc = &Kl[kt & 1][0];
            const bf16_t* Vc = &Vl[kt & 1][0];
            // own loads for tile kt are the only outstanding ones here
            asm volatile("s_waitcnt vmcnt(0)" ::: "memory");
            __builtin_amdgcn_s_barrier();
            if (kt + 1 < nkt) issue_tile((kt + 1) & 1);   // change #1
            __builtin_amdgcn_sched_barrier(0);

            const bool diag = (kt == qt);

            // ---- T = K Q^T per 16-col sub-block; in-reg softmax; cvt_pk ----
            uint32_t u[4][2];
            #pragma unroll
            for (int kb = 0; kb < 4; ++kb) { u[kb][0] = 0; u[kb][1] = 0; }

            #pragma unroll
            for (int kb = 0; kb < 4; ++kb) {
                const bool skip = diag && (kb > fs);
                if (!skip) {
                    f32x4 t = (f32x4){0.f, 0.f, 0.f, 0.f};
                    __builtin_amdgcn_s_setprio(1);
                    #pragma unroll
                    for (int s = 0; s < 4; ++s) {
                        int elem = (s * 32 + l4 * 8) ^ ((l16 & 7) << 3);
                        bf16x8 bk = *(const bf16x8*)(Kc + (kb * 16 + l16) * 128 + elem);
                        t = __builtin_amdgcn_mfma_f32_16x16x32_bf16(bk, aq[s], t, 0, 0, 0);
                    }
                    __builtin_amdgcn_s_setprio(0);
                    const bool needmask = diag && (kb == fs);
                    #pragma unroll
                    for (int j = 0; j < 4; ++j) {
                        float p = exp2f(t[j]);
                        if (needmask && (kb * 16 + l4 * 4 + j > fs * 16 + l16)) p = 0.f;
                        t[j] = p;
                        rsum[j] += p;   // 4 independent chains
                    }
                    u[kb][0] = cvt_pk_bf16(t[0], t[1]);
                    u[kb][1] = cvt_pk_bf16(t[2], t[3]);
                }
            }

            // ---- P -> PV A-frags: IN-LANE (V k-perm makes B match) ----
            bf16x8 pa[2];
            #pragma unroll
            for (int ks = 0; ks < 2; ++ks) {
                union { uint32_t uu[4]; bf16x8 v; } pk;
                pk.uu[0] = u[ks * 2][0];
                pk.uu[1] = u[ks * 2][1];
                pk.uu[2] = u[ks * 2 + 1][0];
                pk.uu[3] = u[ks * 2 + 1][1];
                pa[ks] = pk.v;
            }

            // ---- O += P V ----
            __builtin_amdgcn_s_setprio(1);
            #pragma unroll
            for (int n = 0; n < 8; ++n) {
                #pragma unroll
                for (int ks = 0; ks < 2; ++ks) {
                    int elem = (ks * 32 + l4 * 8) ^ ((l16 & 7) << 3);
                    bf16x8 bv = *(const bf16x8*)(Vc + (n * 16 + l16) * 64 + elem);
                    accO[n] = __builtin_amdgcn_mfma_f32_16x16x32_bf16(pa[ks], bv, accO[n], 0, 0, 0);
                }
            }
            __builtin_amdgcn_s_setprio(0);
            // no end-of-tile barrier (change #1)
        }

        // ---- epilogue: combine partials, reduce over l4 group, store ----
        float rs = (rsum[0] + rsum[1]) + (rsum[2] + rsum[3]);
        rs += __shfl_xor(rs, 16);
        rs += __shfl_xor(rs, 32);
        float inv = 1.f / rs;   // valid for q-row = l16 on every lane
        #pragma unroll
        for (int j = 0; j < 4; ++j) {
            const int qr = l4 * 4 + j;
            float invr = __shfl(inv, qr);   // lane qr holds q-row qr's inv
            float* op = og + (qtok0 + fs * 16 + qr) * QD + h * HDIM + l16;
            #pragma unroll
            for (int n = 0; n < 8; ++n)
                op[n * 16] = accO[n][j] * invr;
        }
    }
}

// ===========================================================================
// Fallback (round-1 kernel) if ws is too small for the bf16 pre-pass.
// ===========================================================================
#define KPAD 136
#define VPAD 72
#define PPAD 72
__global__ __launch_bounds__(512, 2)
void attn_fwd_v1(const float* __restrict__ qg, const float* __restrict__ kg,
                 const float* __restrict__ vg, float* __restrict__ og)
{
    __shared__ bf16_t Kl[KBLK * KPAD];
    __shared__ bf16_t Vt[HDIM * VPAD];
    __shared__ bf16_t Pl[8 * 16 * PPAD];

    const int tid  = threadIdx.x;
    const int w    = tid >> 6;
    const int lane = tid & 63;
    const int l4   = lane >> 4;
    const int l16  = lane & 15;

    const int bid = blockIdx.x;
    const int bh  = bid % 64;
    const int qt  = (NQT - 1) - bid / 64;
    const int b   = bh / NKV;
    const int hk  = bh % NKV;
    const int g   = w >> 1;
    const int h   = hk * GQ + g;
    const int rh  = (w & 1) * 32;

    const long qtok0 = (long)b * SEQ + qt * QBLK;

    bf16x8 aq[2][4];
    #pragma unroll
    for (int f = 0; f < 2; ++f) {
        const float* qp = qg + (qtok0 + rh + f * 16 + l16) * QD + h * HDIM + l4 * 8;
        #pragma unroll
        for (int s = 0; s < 4; ++s) {
            float4 x = *(const float4*)(qp + s * 32);
            float4 y = *(const float4*)(qp + s * 32 + 4);
            bf16x8 t;
            t[0] = (bf16_t)x.x; t[1] = (bf16_t)x.y; t[2] = (bf16_t)x.z; t[3] = (bf16_t)x.w;
            t[4] = (bf16_t)y.x; t[5] = (bf16_t)y.y; t[6] = (bf16_t)y.z; t[7] = (bf16_t)y.w;
            aq[f][s] = t;
        }
    }

    f32x4 accO[2][8];
    float mrun[2][4], lsum[2][4];
    #pragma unroll
    for (int f = 0; f < 2; ++f) {
        #pragma unroll
        for (int n = 0; n < 8; ++n) accO[f][n] = (f32x4){0.f, 0.f, 0.f, 0.f};
        #pragma unroll
        for (int j = 0; j < 4; ++j) { mrun[f][j] = -1e30f; lsum[f][j] = 0.f; }
    }

    const long ktok0 = (long)b * SEQ;
    const int nkt = qt + 1;

    for (int kt = 0; kt < nkt; ++kt) {
        __syncthreads();
        const float* kp = kg + (ktok0 + kt * KBLK) * KVD + hk * HDIM;
        const float* vp = vg + (ktok0 + kt * KBLK) * KVD + hk * HDIM;
        #pragma unroll
        for (int it = 0; it < 4; ++it) {
            int idx = it * 512 + tid;
            int row = idx >> 5;
            int c4  = (idx & 31) * 4;
            float4 kf = *(const float4*)(kp + (long)row * KVD + c4);
            bf16x4 k4;
            k4[0] = (bf16_t)kf.x; k4[1] = (bf16_t)kf.y; k4[2] = (bf16_t)kf.z; k4[3] = (bf16_t)kf.w;
            *(bf16x4*)(&Kl[row * KPAD + c4]) = k4;
            float4 vf = *(const float4*)(vp + (long)row * KVD + c4);
            const float* vfa = (const float*)&vf;
            #pragma unroll
            for (int m = 0; m < 4; ++m) {
                int d   = c4 + m;
                int blk = (row >> 3) ^ ((d >> 3) & 7);
                Vt[d * VPAD + blk * 8 + (row & 7)] = (bf16_t)vfa[m];
            }
        }
        __syncthreads();

        const bool diag = (kt == qt);
        bf16_t* pw = &Pl[w * 16 * PPAD];

        #pragma unroll
        for (int f = 0; f < 2; ++f) {
            f32x4 accS[4];
            #pragma unroll
            for (int n = 0; n < 4; ++n) {
                f32x4 acc = (f32x4){0.f, 0.f, 0.f, 0.f};
                #pragma unroll
                for (int s = 0; s < 4; ++s) {
                    bf16x8 bk = *(const bf16x8*)(&Kl[(n * 16 + l16) * KPAD + s * 32 + l4 * 8]);
                    acc = __builtin_amdgcn_mfma_f32_16x16x32_bf16(aq[f][s], bk, acc, 0, 0, 0);
                }
                accS[n] = acc;
            }

            const int qrow_loc = rh + f * 16 + l4 * 4;
            float pm[4];
            #pragma unroll
            for (int j = 0; j < 4; ++j) pm[j] = -1e30f;
            #pragma unroll
            for (int n = 0; n < 4; ++n) {
                #pragma unroll
                for (int j = 0; j < 4; ++j) {
                    float sv = accS[n][j] * ATT_SCALE;
                    if (diag && (n * 16 + l16 > qrow_loc + j)) sv = -1e30f;
                    accS[n][j] = sv;
                    pm[j] = fmaxf(pm[j], sv);
                }
            }
            #pragma unroll
            for (int j = 0; j < 4; ++j) {
                float m0 = pm[j];
                m0 = fmaxf(m0, __shfl_xor(m0, 1));
                m0 = fmaxf(m0, __shfl_xor(m0, 2));
                m0 = fmaxf(m0, __shfl_xor(m0, 4));
                m0 = fmaxf(m0, __shfl_xor(m0, 8));
                pm[j] = m0;
            }
            float al[4], rs[4];
            #pragma unroll
            for (int j = 0; j < 4; ++j) {
                float mnew = fmaxf(mrun[f][j], pm[j]);
                al[j] = __expf(mrun[f][j] - mnew);
                mrun[f][j] = mnew;
                rs[j] = 0.f;
            }
            #pragma unroll
            for (int n = 0; n < 4; ++n) {
                #pragma unroll
                for (int j = 0; j < 4; ++j) {
                    float p = __expf(accS[n][j] - mrun[f][j]);
                    accS[n][j] = p;
                    rs[j] += p;
                }
            }
            #pragma unroll
            for (int j = 0; j < 4; ++j) {
                float r = rs[j];
                r += __shfl_xor(r, 1);
                r += __shfl_xor(r, 2);
                r += __shfl_xor(r, 4);
                r += __shfl_xor(r, 8);
                lsum[f][j] = lsum[f][j] * al[j] + r;
            }
            #pragma unroll
            for (int n = 0; n < 8; ++n) {
                #pragma unroll
                for (int j = 0; j < 4; ++j) accO[f][n][j] *= al[j];
            }
            #pragma unroll
            for (int n = 0; n < 4; ++n) {
                #pragma unroll
                for (int j = 0; j < 4; ++j)
                    pw[(l4 * 4 + j) * PPAD + n * 16 + l16] = (bf16_t)accS[n][j];
            }
            asm volatile("s_waitcnt lgkmcnt(0)" ::: "memory");
            __builtin_amdgcn_sched_barrier(0);
            #pragma unroll
            for (int ks = 0; ks < 2; ++ks) {
                bf16x8 ap = *(const bf16x8*)(&pw[l16 * PPAD + ks * 32 + l4 * 8]);
                #pragma unroll
                for (int n = 0; n < 8; ++n) {
                    int d   = n * 16 + l16;
                    int blk = (ks * 4 + l4) ^ ((d >> 3) & 7);
                    bf16x8 bv = *(const bf16x8*)(&Vt[d * VPAD + blk * 8]);
                    accO[f][n] = __builtin_amdgcn_mfma_f32_16x16x32_bf16(ap, bv, accO[f][n], 0, 0, 0);
                }
            }
        }
    }

    #pragma unroll
    for (int f = 0; f < 2; ++f) {
        #pragma unroll
        for (int j = 0; j < 4; ++j) {
            float inv = 1.f / lsum[f][j];
            float* op = og + (qtok0 + rh + f * 16 + l4 * 4 + j) * QD + h * HDIM;
            #pragma unroll
            for (int n = 0; n < 8; ++n)
                op[n * 16 + l16] = accO[f][n][j] * inv;
        }
    }
}

extern "C" void kernel_launch(void* const* d_in, const int* in_sizes, int n_in,
                              void* d_out, int out_size, void* d_ws, size_t ws_size,
                              hipStream_t stream) {
    const float* q = (const float*)d_in[0];
    const float* k = (const float*)d_in[1];
    const float* v = (const float*)d_in[2];
    float* o = (float*)d_out;

    const size_t kws_elems = (size_t)TOTAL * KVD;            // 8,388,608
    const size_t vws_elems = (size_t)BATCH * NKV * HDIM * SEQ;
    const size_t need = (kws_elems + vws_elems) * sizeof(bf16_t);  // 33.5 MB

    if (ws_size >= need) {
        bf16_t* kws  = (bf16_t*)d_ws;
        bf16_t* vtws = kws + kws_elems;
        attn_prepass_kernel<<<1536, 256, 0, stream>>>(k, v, kws, vtws);
        attn_fwd_v11<<<1024, 512, 0, stream>>>(q, kws, vtws, o);
    } else {
        attn_fwd_v1<<<NQT * BATCH * NKV, 512, 0, stream>>>(q, k, v, o);
    }
}